// Round 3
// baseline (1074.406 us; speedup 1.0000x reference)
//
#include <hip/hip_runtime.h>
#include <stdint.h>

#define T_ 10
#define B_ 4
#define C_ 384
#define N_ 384
#define H_ 12
#define CN_ 147456      // C_*N_
#define TBCN_ 5898240   // T_*B_*C_*N_
#define BCN_ 589824     // B_*C_*N_
#define PKN_ 184320     // 40*12*384  (packed words per q/k/v array)

typedef short bf16x8 __attribute__((ext_vector_type(8)));
typedef float f32x16 __attribute__((ext_vector_type(16)));

__device__ inline uint16_t f2bf_bits(float f) {
  uint32_t x = __float_as_uint(f);
  uint32_t r = (x + 0x7FFFu + ((x >> 16) & 1u)) >> 16;   // RNE
  return (uint16_t)r;
}
__device__ inline float bf_bits2f(uint16_t u) {
  return __uint_as_float(((uint32_t)u) << 16);
}

// ===========================================================================
// FULL (MFMA) PATH
// ===========================================================================

// Split the 8 conv weights (Sq,Sk,Sv,Tq,Tk,Tv,Sproj,Tproj) into 3 exact bf16
// levels: Wsplit[(conv*3+v)*147456 + oc*384 + k].
__global__ __launch_bounds__(256) void wsplit_kernel(
    const float* __restrict__ sW, const float* __restrict__ tW,
    uint16_t* __restrict__ Wsplit)
{
  const int idx = blockIdx.x * 256 + threadIdx.x;   // < 8*147456 = 1179648
  const int conv = idx / 147456, rem = idx % 147456;
  const float* src;
  switch (conv) {
    case 0: src = sW;          break;
    case 1: src = sW + CN_;    break;
    case 2: src = sW + 2*CN_;  break;
    case 3: src = tW;          break;
    case 4: src = tW + CN_;    break;
    case 5: src = tW + 2*CN_;  break;
    case 6: src = sW + 3*CN_;  break;
    default: src = tW + 3*CN_; break;
  }
  const float w = src[rem];
  const uint16_t b0 = f2bf_bits(w);
  const float r1 = w - bf_bits2f(b0);
  const uint16_t b1 = f2bf_bits(r1);
  const float r2 = r1 - bf_bits2f(b1);
  const uint16_t b2 = f2bf_bits(r2);
  Wsplit[(size_t)(conv*3 + 0)*147456 + rem] = b0;
  Wsplit[(size_t)(conv*3 + 1)*147456 + rem] = b1;
  Wsplit[(size_t)(conv*3 + 2)*147456 + rem] = b2;
}

// Split x,y into 3 exact bf16 levels, TRANSPOSED: XT[inp][v][tb][n][k].
__global__ __launch_bounds__(256) void xsplit_kernel(
    const float* __restrict__ x, const float* __restrict__ y,
    uint16_t* __restrict__ XT)
{
  const int kt = blockIdx.x;            // 0..11 -> k0
  const int nt = blockIdx.y;            // 0..2  -> n0
  const int z  = blockIdx.z;            // 0..79: inp*40+tb
  const int inp = z / 40, tb = z % 40;
  const float* in = (inp ? y : x) + (size_t)tb * CN_;
  const int k0 = kt * 32, n0 = nt * 128;
  __shared__ uint16_t Ls[3][32][132];
  const int tid = threadIdx.x;
  const int kr = tid >> 3, nc = (tid & 7) * 16;
  #pragma unroll
  for (int q = 0; q < 4; q++) {
    const float4 f = *(const float4*)(in + (size_t)(k0 + kr)*384 + n0 + nc + q*4);
    const float vv[4] = {f.x, f.y, f.z, f.w};
    #pragma unroll
    for (int e = 0; e < 4; e++) {
      const float w = vv[e];
      const uint16_t b0 = f2bf_bits(w);
      const float r1 = w - bf_bits2f(b0);
      const uint16_t b1 = f2bf_bits(r1);
      const float r2 = r1 - bf_bits2f(b1);
      Ls[0][kr][nc + q*4 + e] = b0;
      Ls[1][kr][nc + q*4 + e] = b1;
      Ls[2][kr][nc + q*4 + e] = f2bf_bits(r2);
    }
  }
  __syncthreads();
  for (int r = tid; r < 384; r += 256) {
    const int v = r >> 7, n = r & 127;
    uint16_t tmp[32];
    #pragma unroll
    for (int k = 0; k < 32; k++) tmp[k] = Ls[v][k][n];
    uint4* dst = (uint4*)(XT + (((size_t)(inp*3 + v)*40 + tb)*384 + (n0 + n))*384 + k0);
    const uint4* s = (const uint4*)tmp;
    dst[0] = s[0]; dst[1] = s[1]; dst[2] = s[2]; dst[3] = s[3];
  }
}

// conv1 via MFMA: 6 convs, 6-product exact-split bf16 GEMM + BN + LIF ->
// bit-packed spikes. 128x128 tile, 4 waves, BK=16, double-buffered LDS.
__global__ __launch_bounds__(256) void conv1_mfma(
    const uint16_t* __restrict__ Wsplit, const uint16_t* __restrict__ XT,
    const float* __restrict__ sg, const float* __restrict__ sb,
    const float* __restrict__ tg, const float* __restrict__ tb_,
    uint32_t* __restrict__ PSq, uint32_t* __restrict__ PSk, uint32_t* __restrict__ PSv,
    uint32_t* __restrict__ PTq, uint32_t* __restrict__ PTk, uint32_t* __restrict__ PTv)
{
  const int ntile = blockIdx.x, mt = blockIdx.y, tb_i = blockIdx.z;
  const int conv = mt / 3, row0 = (mt % 3) * 128, n0 = ntile * 128;
  const int t = tb_i >> 2, b = tb_i & 3;
  const int slot = (conv < 3) ? conv : conv - 3;
  const int inp = (conv == 0 || conv == 3) ? 0 : 1;

  __shared__ uint8_t lds[49152];                 // 2 x (A 12KB + B 12KB)
  __shared__ float g_l[128], b_l[128];
  const int tid = threadIdx.x, lane = tid & 63, w = tid >> 6;
  const int hi = lane >> 5, l31 = lane & 31;
  const int wr = w >> 1, wc = w & 1;

  const float* gsrc = ((conv < 3) ? sg : tg) + slot*384 + row0;
  const float* bsrc = ((conv < 3) ? sb : tb_) + slot*384 + row0;
  if (tid < 128) g_l[tid] = gsrc[tid];
  else b_l[tid - 128] = bsrc[tid - 128];

  // 24 staging sets per k-step (A: v*4+rb; B: 12 + v*4+cb), 6 per wave.
  const uint16_t* gbase[6]; int ldsoff[6];
  #pragma unroll
  for (int j = 0; j < 6; j++) {
    const int s = w*6 + j;
    if (s < 12) {
      const int v = s >> 2, rb = s & 3;
      gbase[j] = Wsplit + ((size_t)(conv*3 + v)*384 + row0 + rb*32 + l31)*384 + 8*hi;
      ldsoff[j] = s*1024 + lane*16;
    } else {
      const int s2 = s - 12, v = s2 >> 2, cb = s2 & 3;
      gbase[j] = XT + (((size_t)(inp*3 + v)*40 + tb_i)*384 + n0 + cb*32 + l31)*384 + 8*hi;
      ldsoff[j] = 12288 + s2*1024 + lane*16;
    }
  }

  f32x16 acc[2][2];
  #pragma unroll
  for (int i = 0; i < 2; i++)
    #pragma unroll
    for (int j = 0; j < 2; j++)
      #pragma unroll
      for (int e = 0; e < 16; e++) acc[i][j][e] = 0.0f;

  uint4 st[6];
  #pragma unroll
  for (int j = 0; j < 6; j++) st[j] = *(const uint4*)gbase[j];

  for (int ks = 0; ks < 24; ks++) {
    uint8_t* buf = lds + (ks & 1) * 24576;
    #pragma unroll
    for (int j = 0; j < 6; j++) *(uint4*)(buf + ldsoff[j]) = st[j];
    __syncthreads();
    if (ks < 23) {
      #pragma unroll
      for (int j = 0; j < 6; j++)
        st[j] = *(const uint4*)((const uint8_t*)gbase[j] + (size_t)(ks + 1)*32);
    }
    bf16x8 af[2][3], bfv[2][3];
    #pragma unroll
    for (int i = 0; i < 2; i++)
      #pragma unroll
      for (int v = 0; v < 3; v++) {
        af[i][v]  = *(const bf16x8*)(buf + (v*4 + wr*2 + i)*1024 + lane*16);
        bfv[i][v] = *(const bf16x8*)(buf + 12288 + (v*4 + wc*2 + i)*1024 + lane*16);
      }
    #pragma unroll
    for (int i = 0; i < 2; i++)
      #pragma unroll
      for (int j = 0; j < 2; j++) {
        f32x16 c = acc[i][j];
        c = __builtin_amdgcn_mfma_f32_32x32x16_bf16(af[i][0], bfv[j][0], c, 0, 0, 0);
        c = __builtin_amdgcn_mfma_f32_32x32x16_bf16(af[i][0], bfv[j][1], c, 0, 0, 0);
        c = __builtin_amdgcn_mfma_f32_32x32x16_bf16(af[i][1], bfv[j][0], c, 0, 0, 0);
        c = __builtin_amdgcn_mfma_f32_32x32x16_bf16(af[i][0], bfv[j][2], c, 0, 0, 0);
        c = __builtin_amdgcn_mfma_f32_32x32x16_bf16(af[i][1], bfv[j][1], c, 0, 0, 0);
        c = __builtin_amdgcn_mfma_f32_32x32x16_bf16(af[i][2], bfv[j][0], c, 0, 0, 0);
        acc[i][j] = c;
      }
  }

  uint32_t* const outs[6] = {PSq, PSk, PSv, PTq, PTk, PTv};
  uint32_t* Pout = outs[conv];
  #pragma unroll
  for (int i = 0; i < 2; i++) {
    const int rb = wr*2 + i;
    const int h = (row0 >> 5) + rb;
    #pragma unroll
    for (int j = 0; j < 2; j++) {
      const int cb = wc*2 + j;
      uint32_t u = 0;
      #pragma unroll
      for (int reg = 0; reg < 16; reg++) {
        const int row = (reg & 3) + 8*(reg >> 2) + 4*hi;
        const float z = acc[i][j][reg] * g_l[rb*32 + row] + b_l[rb*32 + row];
        u |= (z >= 2.0f ? 1u : 0u) << row;
      }
      u |= (uint32_t)__shfl_xor((int)u, 32, 64);
      if (hi == 0) {
        const int ncol = n0 + cb*32 + l31;
        if (conv < 3) Pout[((size_t)tb_i*12 + h)*384 + ncol] = u;
        else          Pout[(((size_t)b*12 + h)*10 + t)*384 + ncol] = u;
      }
    }
  }
}

// conv4 via MFMA: 3-product exact bf16 GEMM (binary RHS) + BN + LIF -> bytes.
__global__ __launch_bounds__(256) void conv4_mfma(
    const uint16_t* __restrict__ Wsplit, const uint16_t* __restrict__ BT,
    const float* __restrict__ g, const float* __restrict__ bsh,
    uint8_t* __restrict__ Sout, int wconv)
{
  const int ntile = blockIdx.x, mtile = blockIdx.y, tb_i = blockIdx.z;
  const int row0 = mtile * 128, n0 = ntile * 128;

  __shared__ uint8_t lds[32768];                 // 2 x (A 12KB + B 4KB)
  __shared__ float g_l[128], b_l[128];
  const int tid = threadIdx.x, lane = tid & 63, w = tid >> 6;
  const int hi = lane >> 5, l31 = lane & 31;
  const int wr = w >> 1, wc = w & 1;

  if (tid < 128) g_l[tid] = g[row0 + tid];
  else b_l[tid - 128] = bsh[row0 + tid - 128];

  const uint16_t* gbase[4]; int ldsoff[4];
  #pragma unroll
  for (int j = 0; j < 4; j++) {
    const int s = w*4 + j;
    if (s < 12) {
      const int v = s >> 2, rb = s & 3;
      gbase[j] = Wsplit + ((size_t)(wconv*3 + v)*384 + row0 + rb*32 + l31)*384 + 8*hi;
      ldsoff[j] = s*1024 + lane*16;
    } else {
      const int cb = s - 12;
      gbase[j] = BT + ((size_t)tb_i*384 + n0 + cb*32 + l31)*384 + 8*hi;
      ldsoff[j] = 12288 + cb*1024 + lane*16;
    }
  }

  f32x16 acc[2][2];
  #pragma unroll
  for (int i = 0; i < 2; i++)
    #pragma unroll
    for (int j = 0; j < 2; j++)
      #pragma unroll
      for (int e = 0; e < 16; e++) acc[i][j][e] = 0.0f;

  uint4 st[4];
  #pragma unroll
  for (int j = 0; j < 4; j++) st[j] = *(const uint4*)gbase[j];

  for (int ks = 0; ks < 24; ks++) {
    uint8_t* buf = lds + (ks & 1) * 16384;
    #pragma unroll
    for (int j = 0; j < 4; j++) *(uint4*)(buf + ldsoff[j]) = st[j];
    __syncthreads();
    if (ks < 23) {
      #pragma unroll
      for (int j = 0; j < 4; j++)
        st[j] = *(const uint4*)((const uint8_t*)gbase[j] + (size_t)(ks + 1)*32);
    }
    bf16x8 af[2][3], bfv[2];
    #pragma unroll
    for (int i = 0; i < 2; i++) {
      #pragma unroll
      for (int v = 0; v < 3; v++)
        af[i][v] = *(const bf16x8*)(buf + (v*4 + wr*2 + i)*1024 + lane*16);
      bfv[i] = *(const bf16x8*)(buf + 12288 + (wc*2 + i)*1024 + lane*16);
    }
    #pragma unroll
    for (int i = 0; i < 2; i++)
      #pragma unroll
      for (int j = 0; j < 2; j++) {
        f32x16 c = acc[i][j];
        c = __builtin_amdgcn_mfma_f32_32x32x16_bf16(af[i][0], bfv[j], c, 0, 0, 0);
        c = __builtin_amdgcn_mfma_f32_32x32x16_bf16(af[i][1], bfv[j], c, 0, 0, 0);
        c = __builtin_amdgcn_mfma_f32_32x32x16_bf16(af[i][2], bfv[j], c, 0, 0, 0);
        acc[i][j] = c;
      }
  }

  uint8_t* outb = Sout + (size_t)tb_i * CN_;
  #pragma unroll
  for (int i = 0; i < 2; i++) {
    const int rb = wr*2 + i;
    #pragma unroll
    for (int j = 0; j < 2; j++) {
      const int cb = wc*2 + j;
      const int n = n0 + cb*32 + l31;
      #pragma unroll
      for (int reg = 0; reg < 16; reg++) {
        const int row = (reg & 3) + 8*(reg >> 2) + 4*hi;
        const int oc = row0 + rb*32 + row;
        const float z = acc[i][j][reg] * g_l[rb*32 + row] + b_l[rb*32 + row];
        outb[(size_t)oc*384 + n] = (z >= 2.0f) ? 1 : 0;
      }
    }
  }
}

// Spatial attention (exact ints): popcount k^T v, then o = q(k^T v); spike=(o>=8).
// Output bf16 transposed BspT[tb][n][c].
__global__ __launch_bounds__(384) void attn_spatial(
    const uint32_t* __restrict__ PSq, const uint32_t* __restrict__ PSk,
    const uint32_t* __restrict__ PSv, uint16_t* __restrict__ BspT)
{
  const int blk = blockIdx.x;                 // 0..479
  const int h = blk % 12, tb = blk / 12;
  const size_t pbase = ((size_t)tb*12 + h) * 384;

  __shared__ uint32_t qb[384], kb[384], vb[384];
  __shared__ uint32_t knT[32][12], vnT[32][12];
  __shared__ int ktv[32][33];
  const int tid = threadIdx.x;

  qb[tid] = PSq[pbase + tid];
  kb[tid] = PSk[pbase + tid];
  vb[tid] = PSv[pbase + tid];
  __syncthreads();

  {  // column-packed transposes: knT[i][w] bit j = k-bit i of col w*32+j
    const int i = tid & 31, wg = tid >> 5;
    uint32_t kk = 0, vv = 0;
    #pragma unroll
    for (int j = 0; j < 32; j++) {
      kk |= ((kb[wg*32 + j] >> i) & 1u) << j;
      vv |= ((vb[wg*32 + j] >> i) & 1u) << j;
    }
    knT[i][wg] = kk; vnT[i][wg] = vv;
  }
  __syncthreads();

  if (tid < 256) {  // ktv[i][j] = sum_n k[n,i] v[n,j] via popc
    const int i = tid >> 3, j0 = (tid & 7) * 4;
    #pragma unroll
    for (int jj = 0; jj < 4; jj++) {
      int s = 0;
      #pragma unroll
      for (int wg = 0; wg < 12; wg++) s += __popc(knT[i][wg] & vnT[j0 + jj][wg]);
      ktv[i][j0 + jj] = s;
    }
  }
  __syncthreads();

  const int n = tid;
  uint32_t q = qb[n];
  int o[32];
  #pragma unroll
  for (int dd = 0; dd < 32; dd++) o[dd] = 0;
  while (q) {
    const int i = __ffs(q) - 1; q &= q - 1;
    #pragma unroll
    for (int dd = 0; dd < 32; dd++) o[dd] += ktv[i][dd];
  }
  uint16_t rowv[32];
  #pragma unroll
  for (int dd = 0; dd < 32; dd++) rowv[dd] = (o[dd] >= 8) ? 0x3F80 : 0;
  uint4* dst = (uint4*)(BspT + ((size_t)tb*384 + n)*384 + h*32);
  const uint4* s = (const uint4*)rowv;
  dst[0] = s[0]; dst[1] = s[1]; dst[2] = s[2]; dst[3] = s[3];
}

// Temporal attention (exact ints) -> bf16 transposed BtpT[tb2][n][c2]
// via the torch reshape: flat=h*320+t*32+dd -> t2=flat/384, c2=flat%384.
__global__ __launch_bounds__(384) void attn_temporal(
    const uint32_t* __restrict__ PTq, const uint32_t* __restrict__ PTk,
    const uint32_t* __restrict__ PTv, uint16_t* __restrict__ BtpT)
{
  const int n = threadIdx.x;
  const int h = blockIdx.x, b = blockIdx.y;
  const size_t base = ((size_t)b*12 + h) * 10 * 384 + n;

  uint32_t qb[10], kb[10], vb[10];
  #pragma unroll
  for (int t = 0; t < 10; t++) {
    qb[t] = PTq[base + (size_t)t*384];
    kb[t] = PTk[base + (size_t)t*384];
    vb[t] = PTv[base + (size_t)t*384];
  }

  #pragma unroll
  for (int t = 0; t < 10; t++) {
    int o[32];
    #pragma unroll
    for (int dd = 0; dd < 32; dd++) o[dd] = 0;
    #pragma unroll
    for (int s = 0; s < 10; s++) {
      const int a = __popc(qb[t] & kb[s]);
      const uint32_t v = vb[s];
      #pragma unroll
      for (int dd = 0; dd < 32; dd++)
        o[dd] += (int)((v >> dd) & 1) * a;
    }
    uint16_t rowv[32];
    #pragma unroll
    for (int dd = 0; dd < 32; dd++) rowv[dd] = (o[dd] >= 8) ? 0x3F80 : 0;
    const int flat = h*320 + t*32;
    const int t2 = flat / 384, c2 = flat % 384;
    uint4* dst = (uint4*)(BtpT + ((size_t)(t2*4 + b)*384 + n)*384 + c2);
    const uint4* s4 = (const uint4*)rowv;
    dst[0] = s4[0]; dst[1] = s4[1]; dst[2] = s4[2]; dst[3] = s4[3];
  }
}

// ===========================================================================
// R2 FALLBACK PATH (fp32 GEMMs) — used only if ws_size is too small.
// ===========================================================================
__global__ __launch_bounds__(256) void conv1_kernel(
    const float* __restrict__ x, const float* __restrict__ y,
    const float* __restrict__ sW, const float* __restrict__ sg, const float* __restrict__ sb,
    const float* __restrict__ tW, const float* __restrict__ tg, const float* __restrict__ tb_,
    uint32_t* __restrict__ PSq, uint32_t* __restrict__ PSk, uint32_t* __restrict__ PSv,
    uint32_t* __restrict__ PTq, uint32_t* __restrict__ PTk, uint32_t* __restrict__ PTv)
{
  const int ntile = blockIdx.x, mt = blockIdx.y, tb_i = blockIdx.z;
  const int conv = mt / 3, row0 = (mt % 3) * 128;
  const int n0 = ntile * 128;
  const int t = tb_i >> 2, b = tb_i & 3;

  const float* Wb; const float* g; const float* bsh; const float* in;
  int slot; uint32_t* Pout; bool temporal;
  switch (conv) {
    case 0:  Wb = sW;         g = sg; bsh = sb;  in = x; slot = 0; Pout = PSq; temporal = false; break;
    case 1:  Wb = sW + CN_;   g = sg; bsh = sb;  in = y; slot = 1; Pout = PSk; temporal = false; break;
    case 2:  Wb = sW + 2*CN_; g = sg; bsh = sb;  in = y; slot = 2; Pout = PSv; temporal = false; break;
    case 3:  Wb = tW;         g = tg; bsh = tb_; in = x; slot = 0; Pout = PTq; temporal = true;  break;
    case 4:  Wb = tW + CN_;   g = tg; bsh = tb_; in = y; slot = 1; Pout = PTk; temporal = true;  break;
    default: Wb = tW + 2*CN_; g = tg; bsh = tb_; in = y; slot = 2; Pout = PTv; temporal = true;  break;
  }
  const float* inb = in + (size_t)tb_i * CN_;

  __shared__ float As[32][132];
  __shared__ float Bs[32][132];
  float acc[8][8] = {};
  const int tid = threadIdx.x;
  const int tx = tid & 15, ty = tid >> 4;
  const int r0 = ty * 8, c0a = tx * 4, c0b = 64 + tx * 4;
  const int am = tid >> 1, akq = (tid & 1) * 16;
  const int bk = tid >> 3, bc = (tid & 7) * 16;

  for (int k0 = 0; k0 < 384; k0 += 32) {
    #pragma unroll
    for (int q = 0; q < 4; q++) {
      const float4 w4 = *(const float4*)(Wb + (size_t)(row0 + am) * 384 + k0 + akq + q*4);
      As[akq + q*4 + 0][am] = w4.x; As[akq + q*4 + 1][am] = w4.y;
      As[akq + q*4 + 2][am] = w4.z; As[akq + q*4 + 3][am] = w4.w;
    }
    #pragma unroll
    for (int q = 0; q < 4; q++)
      *(float4*)&Bs[bk][bc + q*4] = *(const float4*)(inb + (size_t)(k0 + bk) * 384 + n0 + bc + q*4);
    __syncthreads();
    #pragma unroll
    for (int kk = 0; kk < 32; kk++) {
      float a[8], bv[8];
      *(float4*)&a[0]  = *(const float4*)&As[kk][r0];
      *(float4*)&a[4]  = *(const float4*)&As[kk][r0 + 4];
      *(float4*)&bv[0] = *(const float4*)&Bs[kk][c0a];
      *(float4*)&bv[4] = *(const float4*)&Bs[kk][c0b];
      #pragma unroll
      for (int i = 0; i < 8; i++)
        #pragma unroll
        for (int j = 0; j < 8; j++)
          acc[i][j] = fmaf(a[i], bv[j], acc[i][j]);
    }
    __syncthreads();
  }

  float gg[8], bb[8];
  #pragma unroll
  for (int i = 0; i < 8; i++) {
    const int oc = row0 + r0 + i;
    gg[i] = g[slot*384 + oc]; bb[i] = bsh[slot*384 + oc];
  }
  const int shift = (ty & 3) * 8;
  const int h = (row0 >> 5) + (ty >> 2);
  uint32_t words[8];
  #pragma unroll
  for (int j = 0; j < 8; j++) {
    uint32_t u = 0;
    #pragma unroll
    for (int i = 0; i < 8; i++)
      u |= (uint32_t)((acc[i][j] * gg[i] + bb[i] >= 2.0f) ? 1u : 0u) << i;
    uint32_t wv = u << shift;
    wv |= __shfl_xor(wv, 16, 64);
    wv |= __shfl_xor(wv, 32, 64);
    words[j] = wv;
  }
  if ((ty & 3) == 0) {
    const size_t base = temporal
        ? (((size_t)b * 12 + h) * 10 + t) * 384 + n0
        : ((size_t)tb_i * 12 + h) * 384 + n0;
    #pragma unroll
    for (int j = 0; j < 8; j++) {
      const int c = (j < 4) ? (c0a + j) : (c0b + j - 4);
      Pout[base + c] = words[j];
    }
  }
}

__global__ __launch_bounds__(256) void conv4_kernel(
    const uint8_t* __restrict__ Sin, const float* __restrict__ W,
    const float* __restrict__ g, const float* __restrict__ bsh,
    uint8_t* __restrict__ Sout)
{
  const int ntile = blockIdx.x, mtile = blockIdx.y, tb_i = blockIdx.z;
  const int row0 = mtile * 128, n0 = ntile * 128;
  const uint8_t* inb = Sin + (size_t)tb_i * CN_;

  __shared__ float As[32][132];
  __shared__ float Bs[32][132];
  float acc[8][8] = {};
  const int tid = threadIdx.x;
  const int tx = tid & 15, ty = tid >> 4;
  const int r0 = ty * 8, c0a = tx * 4, c0b = 64 + tx * 4;
  const int am = tid >> 1, akq = (tid & 1) * 16;
  const int bk = tid >> 3, bc = (tid & 7) * 16;

  for (int k0 = 0; k0 < 384; k0 += 32) {
    #pragma unroll
    for (int q = 0; q < 4; q++) {
      const float4 w4 = *(const float4*)(W + (size_t)(row0 + am) * 384 + k0 + akq + q*4);
      As[akq + q*4 + 0][am] = w4.x; As[akq + q*4 + 1][am] = w4.y;
      As[akq + q*4 + 2][am] = w4.z; As[akq + q*4 + 3][am] = w4.w;
    }
    {
      const uint4 u = *(const uint4*)(inb + (size_t)(k0 + bk) * 384 + n0 + bc);
      const uint32_t wd[4] = {u.x, u.y, u.z, u.w};
      #pragma unroll
      for (int q = 0; q < 4; q++) {
        float4 f;
        f.x = (float)( wd[q]        & 0xff);
        f.y = (float)((wd[q] >> 8)  & 0xff);
        f.z = (float)((wd[q] >> 16) & 0xff);
        f.w = (float)((wd[q] >> 24) & 0xff);
        *(float4*)&Bs[bk][bc + q*4] = f;
      }
    }
    __syncthreads();
    #pragma unroll
    for (int kk = 0; kk < 32; kk++) {
      float a[8], bv[8];
      *(float4*)&a[0]  = *(const float4*)&As[kk][r0];
      *(float4*)&a[4]  = *(const float4*)&As[kk][r0 + 4];
      *(float4*)&bv[0] = *(const float4*)&Bs[kk][c0a];
      *(float4*)&bv[4] = *(const float4*)&Bs[kk][c0b];
      #pragma unroll
      for (int i = 0; i < 8; i++)
        #pragma unroll
        for (int j = 0; j < 8; j++)
          acc[i][j] = fmaf(a[i], bv[j], acc[i][j]);
    }
    __syncthreads();
  }

  uint8_t* outb = Sout + (size_t)tb_i * CN_;
  #pragma unroll
  for (int i = 0; i < 8; i++) {
    const int oc = row0 + r0 + i;
    const float ggv = g[oc], bbv = bsh[oc];
    uint32_t pa = 0, pb = 0;
    #pragma unroll
    for (int j = 0; j < 4; j++) {
      pa |= (uint32_t)((acc[i][j]     * ggv + bbv >= 2.0f) ? 1u : 0u) << (8*j);
      pb |= (uint32_t)((acc[i][j + 4] * ggv + bbv >= 2.0f) ? 1u : 0u) << (8*j);
    }
    *(uint32_t*)(outb + (size_t)oc * 384 + n0 + c0a) = pa;
    *(uint32_t*)(outb + (size_t)oc * 384 + n0 + c0b) = pb;
  }
}

__global__ __launch_bounds__(256) void attn_spatial_b(
    const uint32_t* __restrict__ PSq, const uint32_t* __restrict__ PSk,
    const uint32_t* __restrict__ PSv, uint8_t* __restrict__ Osp)
{
  const int blk = blockIdx.x;
  const int h = blk % 12, tb_i = blk / 12;
  const size_t pbase = ((size_t)tb_i * 12 + h) * 384;

  __shared__ uint32_t qb[384], kb[384], vb[384];
  __shared__ int ktv[32][33];
  const int tid = threadIdx.x;

  for (int n = tid; n < 384; n += 256) {
    qb[n] = PSq[pbase + n]; kb[n] = PSk[pbase + n]; vb[n] = PSv[pbase + n];
  }
  __syncthreads();
  {
    const int i = tid >> 3, j0 = (tid & 7) * 4;
    int s0 = 0, s1 = 0, s2 = 0, s3 = 0;
    for (int n = 0; n < 384; n++) {
      const uint32_t m = kb[n] >> i, vv = vb[n] >> j0;
      s0 += (m & vv) & 1;
      s1 += (m & (vv >> 1)) & 1;
      s2 += (m & (vv >> 2)) & 1;
      s3 += (m & (vv >> 3)) & 1;
    }
    ktv[i][j0] = s0; ktv[i][j0+1] = s1; ktv[i][j0+2] = s2; ktv[i][j0+3] = s3;
  }
  __syncthreads();

  uint8_t* outb = Osp + (size_t)tb_i * CN_ + (size_t)h * 32 * 384;
  for (int rep = 0; rep < 48; rep++) {
    const int idx = rep * 256 + tid;
    const int dd = idx / 384, n = idx % 384;
    const uint32_t q = qb[n];
    int o = 0;
    #pragma unroll
    for (int i = 0; i < 32; i++)
      o += ((q >> i) & 1) * ktv[i][dd];
    outb[(size_t)dd * 384 + n] = (o >= 8) ? 1 : 0;
  }
}

__global__ __launch_bounds__(384) void attn_temporal_b(
    const uint32_t* __restrict__ PTq, const uint32_t* __restrict__ PTk,
    const uint32_t* __restrict__ PTv, uint8_t* __restrict__ Otp)
{
  const int n = threadIdx.x;
  const int h = blockIdx.x, b = blockIdx.y;
  const size_t base = (((size_t)b * 12 + h) * 10) * 384 + n;

  uint32_t qb[10], kb[10], vb[10];
  #pragma unroll
  for (int t = 0; t < 10; t++) {
    qb[t] = PTq[base + (size_t)t * 384];
    kb[t] = PTk[base + (size_t)t * 384];
    vb[t] = PTv[base + (size_t)t * 384];
  }
  #pragma unroll
  for (int t = 0; t < 10; t++) {
    int o[32];
    #pragma unroll
    for (int dd = 0; dd < 32; dd++) o[dd] = 0;
    #pragma unroll
    for (int s = 0; s < 10; s++) {
      const int a = __popc(qb[t] & kb[s]);
      const uint32_t v = vb[s];
      #pragma unroll
      for (int dd = 0; dd < 32; dd++)
        o[dd] += (int)((v >> dd) & 1) * a;
    }
    #pragma unroll
    for (int dd = 0; dd < 32; dd++) {
      const int flat = h*320 + t*32 + dd;
      const int t2 = flat / 384, c2 = flat % 384;
      Otp[((size_t)(t2*4 + b) * 384 + c2) * 384 + n] = (o[dd] >= 8) ? 1 : 0;
    }
  }
}

// ===========================================================================
// reductions + final outer product (shared by both paths)
// ===========================================================================
__global__ __launch_bounds__(256) void reduce_a(const uint8_t* __restrict__ a_spike,
                                                float* __restrict__ a_red)
{
  const int row = blockIdx.x * 4 + (threadIdx.x >> 6);
  const int lane = threadIdx.x & 63;
  const uint8_t* p = a_spike + (size_t)row * 384;
  int s = 0;
  #pragma unroll
  for (int i = 0; i < 6; i++) s += p[lane + i*64];
  #pragma unroll
  for (int off = 32; off; off >>= 1) s += __shfl_down(s, off, 64);
  if (lane == 0) a_red[row] = (float)s * (1.0f / 384.0f);
}

__global__ __launch_bounds__(256) void reduce_b(const uint8_t* __restrict__ bt_spike,
                                                float* __restrict__ b_red)
{
  const int idx = blockIdx.x * 256 + threadIdx.x;
  int s = 0;
  #pragma unroll
  for (int t = 0; t < 10; t++) s += bt_spike[(size_t)t * BCN_ + idx];
  b_red[idx] = (float)s * 0.1f;
}

__global__ __launch_bounds__(256) void final_kernel(const float* __restrict__ a_red,
                                                    const float* __restrict__ b_red,
                                                    float* __restrict__ out)
{
  const int idx = blockIdx.x * 256 + threadIdx.x;
  out[idx] = a_red[idx / 384] * b_red[idx % BCN_];
}

// ===========================================================================
extern "C" void kernel_launch(void* const* d_in, const int* in_sizes, int n_in,
                              void* d_out, int out_size, void* d_ws, size_t ws_size,
                              hipStream_t stream) {
  const float* x  = (const float*)d_in[0];
  const float* y  = (const float*)d_in[1];
  const float* sW = (const float*)d_in[2];
  const float* sg = (const float*)d_in[3];
  const float* sb = (const float*)d_in[4];
  const float* tW = (const float*)d_in[5];
  const float* tg = (const float*)d_in[6];
  const float* tb = (const float*)d_in[7];
  float* out = (float*)d_out;

  const size_t NEED_FULL = 121000000;   // ~120.1 MB actually used

  if (ws_size >= NEED_FULL) {
    // ---- full MFMA path ----
    uint16_t* XT   = (uint16_t*)d_ws;              // 35,389,440 elems
    uint16_t* Wsp  = XT + 35389440;                // 3,538,944 elems
    uint32_t* PSq  = (uint32_t*)(Wsp + 3538944);
    uint32_t* PSk  = PSq + PKN_;
    uint32_t* PSv  = PSk + PKN_;
    uint32_t* PTq  = PSv + PKN_;
    uint32_t* PTk  = PTq + PKN_;
    uint32_t* PTv  = PTk + PKN_;
    uint16_t* BspT = (uint16_t*)(PTv + PKN_);      // 5,898,240 elems
    uint16_t* BtpT = BspT + 5898240;
    uint8_t* a_spike  = (uint8_t*)(BtpT + 5898240);
    uint8_t* bt_spike = a_spike + TBCN_;
    float* a_red = (float*)(bt_spike + TBCN_);
    float* b_red = a_red + 15360;

    wsplit_kernel<<<4608, 256, 0, stream>>>(sW, tW, Wsp);
    xsplit_kernel<<<dim3(12, 3, 80), 256, 0, stream>>>(x, y, XT);
    conv1_mfma<<<dim3(3, 18, 40), 256, 0, stream>>>(Wsp, XT, sg, sb, tg, tb,
                                                    PSq, PSk, PSv, PTq, PTk, PTv);
    attn_spatial<<<480, 384, 0, stream>>>(PSq, PSk, PSv, BspT);
    attn_temporal<<<dim3(12, 4), 384, 0, stream>>>(PTq, PTk, PTv, BtpT);
    conv4_mfma<<<dim3(3, 3, 40), 256, 0, stream>>>(Wsp, BspT, sg + 3*384, sb + 3*384, a_spike, 6);
    conv4_mfma<<<dim3(3, 3, 40), 256, 0, stream>>>(Wsp, BtpT, tg + 3*384, tb + 3*384, bt_spike, 7);
    reduce_a<<<3840, 256, 0, stream>>>(a_spike, a_red);
    reduce_b<<<2304, 256, 0, stream>>>(bt_spike, b_red);
    final_kernel<<<23040, 256, 0, stream>>>(a_red, b_red, out);
  } else {
    // ---- R2 fallback (fp32 GEMMs) ----
    uint32_t* PSq = (uint32_t*)d_ws;
    uint32_t* PSk = PSq + PKN_;
    uint32_t* PSv = PSk + PKN_;
    uint32_t* PTq = PSv + PKN_;
    uint32_t* PTk = PTq + PKN_;
    uint32_t* PTv = PTk + PKN_;
    float* a_red = (float*)(PTv + PKN_);
    float* b_red = a_red + 15360;
    uint8_t* Osp      = (uint8_t*)(b_red + BCN_);
    uint8_t* Otp      = Osp + TBCN_;
    uint8_t* a_spike  = Otp + TBCN_;
    uint8_t* bt_spike = a_spike + TBCN_;

    conv1_kernel<<<dim3(3, 18, 40), 256, 0, stream>>>(x, y, sW, sg, sb, tW, tg, tb,
                                                      PSq, PSk, PSv, PTq, PTk, PTv);
    attn_spatial_b<<<480, 256, 0, stream>>>(PSq, PSk, PSv, Osp);
    attn_temporal_b<<<dim3(12, 4), 384, 0, stream>>>(PTq, PTk, PTv, Otp);
    conv4_kernel<<<dim3(3, 3, 40), 256, 0, stream>>>(Osp, sW + 3*CN_, sg + 3*384, sb + 3*384, a_spike);
    conv4_kernel<<<dim3(3, 3, 40), 256, 0, stream>>>(Otp, tW + 3*CN_, tg + 3*384, tb + 3*384, bt_spike);
    reduce_a<<<3840, 256, 0, stream>>>(a_spike, a_red);
    reduce_b<<<2304, 256, 0, stream>>>(bt_spike, b_red);
    final_kernel<<<23040, 256, 0, stream>>>(a_red, b_red, out);
  }
}

// Round 4
// 527.636 us; speedup vs baseline: 2.0363x; 2.0363x over previous
//
#include <hip/hip_runtime.h>
#include <stdint.h>

#define T_ 10
#define B_ 4
#define C_ 384
#define N_ 384
#define H_ 12
#define CN_ 147456      // C_*N_
#define TBCN_ 5898240   // T_*B_*C_*N_
#define BCN_ 589824     // B_*C_*N_
#define PKN_ 184320     // 40*12*384  (packed words per q/k/v array)

typedef short bf16x8 __attribute__((ext_vector_type(8)));
typedef float f32x16 __attribute__((ext_vector_type(16)));

__device__ inline uint16_t f2bf_bits(float f) {
  uint32_t x = __float_as_uint(f);
  uint32_t r = (x + 0x7FFFu + ((x >> 16) & 1u)) >> 16;   // RNE
  return (uint16_t)r;
}
__device__ inline float bf_bits2f(uint16_t u) {
  return __uint_as_float(((uint32_t)u) << 16);
}

// async global->LDS, 16B per lane; LDS dest must be wave-uniform base + lane*16
__device__ inline void gload_lds16(const void* g, void* l) {
  __builtin_amdgcn_global_load_lds(
      (const __attribute__((address_space(1))) uint32_t*)g,
      (__attribute__((address_space(3))) uint32_t*)l, 16, 0, 0);
}

// ===========================================================================
// Weight split: 8 convs (Sq,Sk,Sv,Tq,Tk,Tv,Sproj,Tproj) -> 3 exact bf16 levels
// Wsplit[(conv*3+v)*147456 + oc*384 + k].
// ===========================================================================
__global__ __launch_bounds__(256) void wsplit_kernel(
    const float* __restrict__ sW, const float* __restrict__ tW,
    uint16_t* __restrict__ Wsplit)
{
  const int idx = blockIdx.x * 256 + threadIdx.x;   // < 8*147456
  const int conv = idx / 147456, rem = idx % 147456;
  const float* src;
  switch (conv) {
    case 0: src = sW;          break;
    case 1: src = sW + CN_;    break;
    case 2: src = sW + 2*CN_;  break;
    case 3: src = tW;          break;
    case 4: src = tW + CN_;    break;
    case 5: src = tW + 2*CN_;  break;
    case 6: src = sW + 3*CN_;  break;
    default: src = tW + 3*CN_; break;
  }
  const float w = src[rem];
  const uint16_t b0 = f2bf_bits(w);
  const float r1 = w - bf_bits2f(b0);
  const uint16_t b1 = f2bf_bits(r1);
  const float r2 = r1 - bf_bits2f(b1);
  const uint16_t b2 = f2bf_bits(r2);
  Wsplit[(size_t)(conv*3 + 0)*147456 + rem] = b0;
  Wsplit[(size_t)(conv*3 + 1)*147456 + rem] = b1;
  Wsplit[(size_t)(conv*3 + 2)*147456 + rem] = b2;
}

// Split x,y into 3 exact bf16 levels, TRANSPOSED: XT[inp][v][tb][n][k].
__global__ __launch_bounds__(256) void xsplit_kernel(
    const float* __restrict__ x, const float* __restrict__ y,
    uint16_t* __restrict__ XT)
{
  const int kt = blockIdx.x;            // 0..11 -> k0
  const int nt = blockIdx.y;            // 0..2  -> n0
  const int z  = blockIdx.z;            // 0..79: inp*40+tb
  const int inp = z / 40, tb = z % 40;
  const float* in = (inp ? y : x) + (size_t)tb * CN_;
  const int k0 = kt * 32, n0 = nt * 128;
  __shared__ uint16_t Ls[3][32][132];
  const int tid = threadIdx.x;
  const int kr = tid >> 3, nc = (tid & 7) * 16;
  #pragma unroll
  for (int q = 0; q < 4; q++) {
    const float4 f = *(const float4*)(in + (size_t)(k0 + kr)*384 + n0 + nc + q*4);
    const float vv[4] = {f.x, f.y, f.z, f.w};
    #pragma unroll
    for (int e = 0; e < 4; e++) {
      const float w = vv[e];
      const uint16_t b0 = f2bf_bits(w);
      const float r1 = w - bf_bits2f(b0);
      const uint16_t b1 = f2bf_bits(r1);
      const float r2 = r1 - bf_bits2f(b1);
      Ls[0][kr][nc + q*4 + e] = b0;
      Ls[1][kr][nc + q*4 + e] = b1;
      Ls[2][kr][nc + q*4 + e] = f2bf_bits(r2);
    }
  }
  __syncthreads();
  for (int r = tid; r < 384; r += 256) {
    const int v = r >> 7, n = r & 127;
    uint16_t tmp[32];
    #pragma unroll
    for (int k = 0; k < 32; k++) tmp[k] = Ls[v][k][n];
    uint4* dst = (uint4*)(XT + (((size_t)(inp*3 + v)*40 + tb)*384 + (n0 + n))*384 + k0);
    const uint4* s = (const uint4*)tmp;
    dst[0] = s[0]; dst[1] = s[1]; dst[2] = s[2]; dst[3] = s[3];
  }
}

// ===========================================================================
// conv1 via MFMA: 6 convs, 6-product exact-split bf16 GEMM + BN + LIF ->
// bit-packed spikes. 128x128 tile, 4 waves, BK=16, dbuf LDS via
// global_load_lds (no staging VGPRs -> no spills). Grid: x = mt*3+ntile
// (W-reuse window contiguous), y = tb.
// ===========================================================================
__global__ __launch_bounds__(256) void conv1_mfma(
    const uint16_t* __restrict__ Wsplit, const uint16_t* __restrict__ XT,
    const float* __restrict__ sg, const float* __restrict__ sb,
    const float* __restrict__ tg, const float* __restrict__ tb_,
    uint32_t* __restrict__ PSq, uint32_t* __restrict__ PSk, uint32_t* __restrict__ PSv,
    uint32_t* __restrict__ PTq, uint32_t* __restrict__ PTk, uint32_t* __restrict__ PTv)
{
  const int xi = blockIdx.x;             // 0..53
  const int mt = xi / 3, ntile = xi % 3;
  const int tb_i = blockIdx.y;           // 0..39
  const int conv = mt / 3, row0 = (mt % 3) * 128, n0 = ntile * 128;
  const int t = tb_i >> 2, b = tb_i & 3;
  const int slot = (conv < 3) ? conv : conv - 3;
  const int inp = (conv == 0 || conv == 3) ? 0 : 1;

  __shared__ uint8_t lds[49152];                 // 2 x (A 12KB + B 12KB)
  __shared__ float g_l[128], b_l[128];
  const int tid = threadIdx.x, lane = tid & 63, w = tid >> 6;
  const int hi = lane >> 5, l31 = lane & 31;
  const int wr = w >> 1, wc = w & 1;

  const float* gsrc = ((conv < 3) ? sg : tg) + slot*384 + row0;
  const float* bsrc = ((conv < 3) ? sb : tb_) + slot*384 + row0;
  if (tid < 128) g_l[tid] = gsrc[tid];
  else b_l[tid - 128] = bsrc[tid - 128];

  // 24 staging sets per k-step (A: s=v*4+rb in [0,12); B: 12 + v*4+cb), 6/wave
  const uint8_t* gp[6]; uint32_t loff[6];
  #pragma unroll
  for (int j = 0; j < 6; j++) {
    const int s = w*6 + j;
    if (s < 12) {
      const int v = s >> 2, rb = s & 3;
      gp[j] = (const uint8_t*)(Wsplit + ((size_t)(conv*3 + v)*384 + row0 + rb*32 + l31)*384 + 8*hi);
      loff[j] = (uint32_t)(s*1024 + lane*16);
    } else {
      const int s2 = s - 12, v = s2 >> 2, cb = s2 & 3;
      gp[j] = (const uint8_t*)(XT + (((size_t)(inp*3 + v)*40 + tb_i)*384 + n0 + cb*32 + l31)*384 + 8*hi);
      loff[j] = (uint32_t)(12288 + s2*1024 + lane*16);
    }
  }

  f32x16 acc[2][2];
  #pragma unroll
  for (int i = 0; i < 2; i++)
    #pragma unroll
    for (int j = 0; j < 2; j++)
      #pragma unroll
      for (int e = 0; e < 16; e++) acc[i][j][e] = 0.0f;

  // prologue: stage ks=0 into buf0
  #pragma unroll
  for (int j = 0; j < 6; j++) gload_lds16(gp[j], &lds[loff[j]]);

  for (int ks = 0; ks < 24; ks++) {
    uint8_t* buf = &lds[(ks & 1) * 24576];
    __syncthreads();                       // drains vmcnt (staging of buf) + lgkm
    if (ks < 23) {
      uint8_t* nb = &lds[((ks + 1) & 1) * 24576];
      #pragma unroll
      for (int j = 0; j < 6; j++)
        gload_lds16(gp[j] + (size_t)(ks + 1) * 32, &nb[loff[j]]);
    }
    bf16x8 af[2][3], bfv[2][3];
    #pragma unroll
    for (int i = 0; i < 2; i++)
      #pragma unroll
      for (int v = 0; v < 3; v++) {
        af[i][v]  = *(const bf16x8*)(buf + (v*4 + wr*2 + i)*1024 + lane*16);
        bfv[i][v] = *(const bf16x8*)(buf + 12288 + (v*4 + wc*2 + i)*1024 + lane*16);
      }
    #pragma unroll
    for (int i = 0; i < 2; i++)
      #pragma unroll
      for (int j = 0; j < 2; j++) {
        f32x16 c = acc[i][j];
        c = __builtin_amdgcn_mfma_f32_32x32x16_bf16(af[i][0], bfv[j][0], c, 0, 0, 0);
        c = __builtin_amdgcn_mfma_f32_32x32x16_bf16(af[i][0], bfv[j][1], c, 0, 0, 0);
        c = __builtin_amdgcn_mfma_f32_32x32x16_bf16(af[i][1], bfv[j][0], c, 0, 0, 0);
        c = __builtin_amdgcn_mfma_f32_32x32x16_bf16(af[i][0], bfv[j][2], c, 0, 0, 0);
        c = __builtin_amdgcn_mfma_f32_32x32x16_bf16(af[i][1], bfv[j][1], c, 0, 0, 0);
        c = __builtin_amdgcn_mfma_f32_32x32x16_bf16(af[i][2], bfv[j][0], c, 0, 0, 0);
        acc[i][j] = c;
      }
  }

  uint32_t* Pout;
  switch (conv) {
    case 0: Pout = PSq; break;
    case 1: Pout = PSk; break;
    case 2: Pout = PSv; break;
    case 3: Pout = PTq; break;
    case 4: Pout = PTk; break;
    default: Pout = PTv; break;
  }
  #pragma unroll
  for (int i = 0; i < 2; i++) {
    const int rb = wr*2 + i;
    const int h = (row0 >> 5) + rb;
    #pragma unroll
    for (int j = 0; j < 2; j++) {
      const int cb = wc*2 + j;
      uint32_t u = 0;
      #pragma unroll
      for (int reg = 0; reg < 16; reg++) {
        const int row = (reg & 3) + 8*(reg >> 2) + 4*hi;
        const float z = acc[i][j][reg] * g_l[rb*32 + row] + b_l[rb*32 + row];
        u |= (z >= 2.0f ? 1u : 0u) << row;
      }
      u |= (uint32_t)__shfl_xor((int)u, 32, 64);
      if (hi == 0) {
        const int ncol = n0 + cb*32 + l31;
        if (conv < 3) Pout[((size_t)tb_i*12 + h)*384 + ncol] = u;
        else          Pout[(((size_t)b*12 + h)*10 + t)*384 + ncol] = u;
      }
    }
  }
}

// ===========================================================================
// conv4 via MFMA: 3-product exact bf16 GEMM (binary RHS) + BN + LIF -> bytes.
// Grid: x = mtile*3+ntile, y = tb.
// ===========================================================================
__global__ __launch_bounds__(256) void conv4_mfma(
    const uint16_t* __restrict__ Wsplit, const uint16_t* __restrict__ BT,
    const float* __restrict__ g, const float* __restrict__ bsh,
    uint8_t* __restrict__ Sout, int wconv)
{
  const int xi = blockIdx.x;             // 0..8
  const int mtile = xi / 3, ntile = xi % 3;
  const int tb_i = blockIdx.y;           // 0..39
  const int row0 = mtile * 128, n0 = ntile * 128;

  __shared__ uint8_t lds[32768];                 // 2 x (A 12KB + B 4KB)
  __shared__ float g_l[128], b_l[128];
  const int tid = threadIdx.x, lane = tid & 63, w = tid >> 6;
  const int hi = lane >> 5, l31 = lane & 31;
  const int wr = w >> 1, wc = w & 1;

  if (tid < 128) g_l[tid] = g[row0 + tid];
  else b_l[tid - 128] = bsh[row0 + tid - 128];

  const uint8_t* gp[4]; uint32_t loff[4];
  #pragma unroll
  for (int j = 0; j < 4; j++) {
    const int s = w*4 + j;
    if (s < 12) {
      const int v = s >> 2, rb = s & 3;
      gp[j] = (const uint8_t*)(Wsplit + ((size_t)(wconv*3 + v)*384 + row0 + rb*32 + l31)*384 + 8*hi);
      loff[j] = (uint32_t)(s*1024 + lane*16);
    } else {
      const int cb = s - 12;
      gp[j] = (const uint8_t*)(BT + ((size_t)tb_i*384 + n0 + cb*32 + l31)*384 + 8*hi);
      loff[j] = (uint32_t)(12288 + cb*1024 + lane*16);
    }
  }

  f32x16 acc[2][2];
  #pragma unroll
  for (int i = 0; i < 2; i++)
    #pragma unroll
    for (int j = 0; j < 2; j++)
      #pragma unroll
      for (int e = 0; e < 16; e++) acc[i][j][e] = 0.0f;

  #pragma unroll
  for (int j = 0; j < 4; j++) gload_lds16(gp[j], &lds[loff[j]]);

  for (int ks = 0; ks < 24; ks++) {
    uint8_t* buf = &lds[(ks & 1) * 16384];
    __syncthreads();
    if (ks < 23) {
      uint8_t* nb = &lds[((ks + 1) & 1) * 16384];
      #pragma unroll
      for (int j = 0; j < 4; j++)
        gload_lds16(gp[j] + (size_t)(ks + 1) * 32, &nb[loff[j]]);
    }
    bf16x8 af[2][3], bfv[2];
    #pragma unroll
    for (int i = 0; i < 2; i++) {
      #pragma unroll
      for (int v = 0; v < 3; v++)
        af[i][v] = *(const bf16x8*)(buf + (v*4 + wr*2 + i)*1024 + lane*16);
      bfv[i] = *(const bf16x8*)(buf + 12288 + (wc*2 + i)*1024 + lane*16);
    }
    #pragma unroll
    for (int i = 0; i < 2; i++)
      #pragma unroll
      for (int j = 0; j < 2; j++) {
        f32x16 c = acc[i][j];
        c = __builtin_amdgcn_mfma_f32_32x32x16_bf16(af[i][0], bfv[j], c, 0, 0, 0);
        c = __builtin_amdgcn_mfma_f32_32x32x16_bf16(af[i][1], bfv[j], c, 0, 0, 0);
        c = __builtin_amdgcn_mfma_f32_32x32x16_bf16(af[i][2], bfv[j], c, 0, 0, 0);
        acc[i][j] = c;
      }
  }

  uint8_t* outb = Sout + (size_t)tb_i * CN_;
  #pragma unroll
  for (int i = 0; i < 2; i++) {
    const int rb = wr*2 + i;
    #pragma unroll
    for (int j = 0; j < 2; j++) {
      const int cb = wc*2 + j;
      const int n = n0 + cb*32 + l31;
      #pragma unroll
      for (int reg = 0; reg < 16; reg++) {
        const int row = (reg & 3) + 8*(reg >> 2) + 4*hi;
        const int oc = row0 + rb*32 + row;
        const float z = acc[i][j][reg] * g_l[rb*32 + row] + b_l[rb*32 + row];
        outb[(size_t)oc*384 + n] = (z >= 2.0f) ? 1 : 0;
      }
    }
  }
}

// ===========================================================================
// Spatial attention (exact ints): popcount k^T v, o = q(k^T v); spike=(o>=8).
// Output bf16 transposed BspT[tb][n][c].
// ===========================================================================
__global__ __launch_bounds__(384) void attn_spatial(
    const uint32_t* __restrict__ PSq, const uint32_t* __restrict__ PSk,
    const uint32_t* __restrict__ PSv, uint16_t* __restrict__ BspT)
{
  const int blk = blockIdx.x;                 // 0..479
  const int h = blk % 12, tb = blk / 12;
  const size_t pbase = ((size_t)tb*12 + h) * 384;

  __shared__ uint32_t qb[384], kb[384], vb[384];
  __shared__ uint32_t knT[32][12], vnT[32][12];
  __shared__ int ktv[32][33];
  const int tid = threadIdx.x;

  qb[tid] = PSq[pbase + tid];
  kb[tid] = PSk[pbase + tid];
  vb[tid] = PSv[pbase + tid];
  __syncthreads();

  {  // column-packed transposes
    const int i = tid & 31, wg = tid >> 5;
    uint32_t kk = 0, vv = 0;
    #pragma unroll
    for (int j = 0; j < 32; j++) {
      kk |= ((kb[wg*32 + j] >> i) & 1u) << j;
      vv |= ((vb[wg*32 + j] >> i) & 1u) << j;
    }
    knT[i][wg] = kk; vnT[i][wg] = vv;
  }
  __syncthreads();

  if (tid < 256) {  // ktv[i][j] = sum_n k[n,i] v[n,j]
    const int i = tid >> 3, j0 = (tid & 7) * 4;
    #pragma unroll
    for (int jj = 0; jj < 4; jj++) {
      int s = 0;
      #pragma unroll
      for (int wg = 0; wg < 12; wg++) s += __popc(knT[i][wg] & vnT[j0 + jj][wg]);
      ktv[i][j0 + jj] = s;
    }
  }
  __syncthreads();

  const int n = tid;
  uint32_t q = qb[n];
  int o[32];
  #pragma unroll
  for (int dd = 0; dd < 32; dd++) o[dd] = 0;
  while (q) {
    const int i = __ffs(q) - 1; q &= q - 1;
    #pragma unroll
    for (int dd = 0; dd < 32; dd++) o[dd] += ktv[i][dd];
  }
  uint16_t rowv[32];
  #pragma unroll
  for (int dd = 0; dd < 32; dd++) rowv[dd] = (o[dd] >= 8) ? 0x3F80 : 0;
  uint4* dst = (uint4*)(BspT + ((size_t)tb*384 + n)*384 + h*32);
  const uint4* s = (const uint4*)rowv;
  dst[0] = s[0]; dst[1] = s[1]; dst[2] = s[2]; dst[3] = s[3];
}

// Temporal attention (exact ints) -> bf16 transposed BtpT[tb2][n][c2].
__global__ __launch_bounds__(384) void attn_temporal(
    const uint32_t* __restrict__ PTq, const uint32_t* __restrict__ PTk,
    const uint32_t* __restrict__ PTv, uint16_t* __restrict__ BtpT)
{
  const int n = threadIdx.x;
  const int h = blockIdx.x, b = blockIdx.y;
  const size_t base = ((size_t)b*12 + h) * 10 * 384 + n;

  uint32_t qb[10], kb[10], vb[10];
  #pragma unroll
  for (int t = 0; t < 10; t++) {
    qb[t] = PTq[base + (size_t)t*384];
    kb[t] = PTk[base + (size_t)t*384];
    vb[t] = PTv[base + (size_t)t*384];
  }

  #pragma unroll
  for (int t = 0; t < 10; t++) {
    int o[32];
    #pragma unroll
    for (int dd = 0; dd < 32; dd++) o[dd] = 0;
    #pragma unroll
    for (int s = 0; s < 10; s++) {
      const int a = __popc(qb[t] & kb[s]);
      const uint32_t v = vb[s];
      #pragma unroll
      for (int dd = 0; dd < 32; dd++)
        o[dd] += (int)((v >> dd) & 1) * a;
    }
    uint16_t rowv[32];
    #pragma unroll
    for (int dd = 0; dd < 32; dd++) rowv[dd] = (o[dd] >= 8) ? 0x3F80 : 0;
    const int flat = h*320 + t*32;
    const int t2 = flat / 384, c2 = flat % 384;
    uint4* dst = (uint4*)(BtpT + ((size_t)(t2*4 + b)*384 + n)*384 + c2);
    const uint4* s4 = (const uint4*)rowv;
    dst[0] = s4[0]; dst[1] = s4[1]; dst[2] = s4[2]; dst[3] = s4[3];
  }
}

// ===========================================================================
// reductions + final outer product
// ===========================================================================
__global__ __launch_bounds__(256) void reduce_a(const uint8_t* __restrict__ a_spike,
                                                float* __restrict__ a_red)
{
  const int row = blockIdx.x * 4 + (threadIdx.x >> 6);
  const int lane = threadIdx.x & 63;
  const uint8_t* p = a_spike + (size_t)row * 384;
  int s = 0;
  #pragma unroll
  for (int i = 0; i < 6; i++) s += p[lane + i*64];
  #pragma unroll
  for (int off = 32; off; off >>= 1) s += __shfl_down(s, off, 64);
  if (lane == 0) a_red[row] = (float)s * (1.0f / 384.0f);
}

__global__ __launch_bounds__(256) void reduce_b(const uint8_t* __restrict__ bt_spike,
                                                float* __restrict__ b_red)
{
  const int idx = blockIdx.x * 256 + threadIdx.x;
  int s = 0;
  #pragma unroll
  for (int t = 0; t < 10; t++) s += bt_spike[(size_t)t * BCN_ + idx];
  b_red[idx] = (float)s * 0.1f;
}

__global__ __launch_bounds__(256) void final_kernel(const float* __restrict__ a_red,
                                                    const float* __restrict__ b_red,
                                                    float* __restrict__ out)
{
  const int idx = blockIdx.x * 256 + threadIdx.x;
  out[idx] = a_red[idx / 384] * b_red[idx % BCN_];
}

// ===========================================================================
extern "C" void kernel_launch(void* const* d_in, const int* in_sizes, int n_in,
                              void* d_out, int out_size, void* d_ws, size_t ws_size,
                              hipStream_t stream) {
  const float* x  = (const float*)d_in[0];
  const float* y  = (const float*)d_in[1];
  const float* sW = (const float*)d_in[2];
  const float* sg = (const float*)d_in[3];
  const float* sb = (const float*)d_in[4];
  const float* tW = (const float*)d_in[5];
  const float* tg = (const float*)d_in[6];
  const float* tb = (const float*)d_in[7];
  float* out = (float*)d_out;

  uint16_t* XT   = (uint16_t*)d_ws;              // 35,389,440 elems
  uint16_t* Wsp  = XT + 35389440;                // 3,538,944 elems
  uint32_t* PSq  = (uint32_t*)(Wsp + 3538944);
  uint32_t* PSk  = PSq + PKN_;
  uint32_t* PSv  = PSk + PKN_;
  uint32_t* PTq  = PSv + PKN_;
  uint32_t* PTk  = PTq + PKN_;
  uint32_t* PTv  = PTk + PKN_;
  uint16_t* BspT = (uint16_t*)(PTv + PKN_);      // 5,898,240 elems
  uint16_t* BtpT = BspT + 5898240;
  uint8_t* a_spike  = (uint8_t*)(BtpT + 5898240);
  uint8_t* bt_spike = a_spike + TBCN_;
  float* a_red = (float*)(bt_spike + TBCN_);
  float* b_red = a_red + 15360;

  wsplit_kernel<<<4608, 256, 0, stream>>>(sW, tW, Wsp);
  xsplit_kernel<<<dim3(12, 3, 80), 256, 0, stream>>>(x, y, XT);
  conv1_mfma<<<dim3(54, 40), 256, 0, stream>>>(Wsp, XT, sg, sb, tg, tb,
                                               PSq, PSk, PSv, PTq, PTk, PTv);
  attn_spatial<<<480, 384, 0, stream>>>(PSq, PSk, PSv, BspT);
  attn_temporal<<<dim3(12, 4), 384, 0, stream>>>(PTq, PTk, PTv, BtpT);
  conv4_mfma<<<dim3(9, 40), 256, 0, stream>>>(Wsp, BspT, sg + 3*384, sb + 3*384, a_spike, 6);
  conv4_mfma<<<dim3(9, 40), 256, 0, stream>>>(Wsp, BtpT, tg + 3*384, tb + 3*384, bt_spike, 7);
  reduce_a<<<3840, 256, 0, stream>>>(a_spike, a_red);
  reduce_b<<<2304, 256, 0, stream>>>(bt_spike, b_red);
  final_kernel<<<23040, 256, 0, stream>>>(a_red, b_red, out);
}

// Round 5
// 471.511 us; speedup vs baseline: 2.2786x; 1.1190x over previous
//
#include <hip/hip_runtime.h>
#include <stdint.h>

#define T_ 10
#define B_ 4
#define C_ 384
#define N_ 384
#define H_ 12
#define CN_ 147456      // C_*N_
#define TBCN_ 5898240   // T_*B_*C_*N_
#define BCN_ 589824     // B_*C_*N_
#define PKN_ 184320     // 40*12*384  (packed words per q/k/v array)

typedef short bf16x8 __attribute__((ext_vector_type(8)));
typedef float f32x16 __attribute__((ext_vector_type(16)));

#define VMCNT(N) asm volatile("s_waitcnt vmcnt(" #N ")" ::: "memory")
#define SBAR()   __builtin_amdgcn_s_barrier()
#define SCHEDB() __builtin_amdgcn_sched_barrier(0)

__device__ inline uint16_t f2bf_bits(float f) {
  uint32_t x = __float_as_uint(f);
  uint32_t r = (x + 0x7FFFu + ((x >> 16) & 1u)) >> 16;   // RNE
  return (uint16_t)r;
}
__device__ inline float bf_bits2f(uint16_t u) {
  return __uint_as_float(((uint32_t)u) << 16);
}

// async global->LDS, 16B per lane; LDS dest must be wave-uniform base + lane*16
__device__ inline void gload_lds16(const void* g, void* l) {
  __builtin_amdgcn_global_load_lds(
      (const __attribute__((address_space(1))) uint32_t*)g,
      (__attribute__((address_space(3))) uint32_t*)l, 16, 0, 0);
}

// ===========================================================================
// Weight split: 8 convs (Sq,Sk,Sv,Tq,Tk,Tv,Sproj,Tproj) -> 3 exact bf16 levels
// ===========================================================================
__global__ __launch_bounds__(256) void wsplit_kernel(
    const float* __restrict__ sW, const float* __restrict__ tW,
    uint16_t* __restrict__ Wsplit)
{
  const int idx = blockIdx.x * 256 + threadIdx.x;   // < 8*147456
  const int conv = idx / 147456, rem = idx % 147456;
  const float* src;
  switch (conv) {
    case 0: src = sW;          break;
    case 1: src = sW + CN_;    break;
    case 2: src = sW + 2*CN_;  break;
    case 3: src = tW;          break;
    case 4: src = tW + CN_;    break;
    case 5: src = tW + 2*CN_;  break;
    case 6: src = sW + 3*CN_;  break;
    default: src = tW + 3*CN_; break;
  }
  const float w = src[rem];
  const uint16_t b0 = f2bf_bits(w);
  const float r1 = w - bf_bits2f(b0);
  const uint16_t b1 = f2bf_bits(r1);
  const float r2 = r1 - bf_bits2f(b1);
  const uint16_t b2 = f2bf_bits(r2);
  Wsplit[(size_t)(conv*3 + 0)*147456 + rem] = b0;
  Wsplit[(size_t)(conv*3 + 1)*147456 + rem] = b1;
  Wsplit[(size_t)(conv*3 + 2)*147456 + rem] = b2;
}

// Split x,y into 3 exact bf16 levels, TRANSPOSED: XT[inp][v][tb][n][k].
__global__ __launch_bounds__(256) void xsplit_kernel(
    const float* __restrict__ x, const float* __restrict__ y,
    uint16_t* __restrict__ XT)
{
  const int kt = blockIdx.x;            // 0..11 -> k0
  const int nt = blockIdx.y;            // 0..2  -> n0
  const int z  = blockIdx.z;            // 0..79: inp*40+tb
  const int inp = z / 40, tb = z % 40;
  const float* in = (inp ? y : x) + (size_t)tb * CN_;
  const int k0 = kt * 32, n0 = nt * 128;
  __shared__ uint16_t Ls[3][32][132];
  const int tid = threadIdx.x;
  const int kr = tid >> 3, nc = (tid & 7) * 16;
  #pragma unroll
  for (int q = 0; q < 4; q++) {
    const float4 f = *(const float4*)(in + (size_t)(k0 + kr)*384 + n0 + nc + q*4);
    const float vv[4] = {f.x, f.y, f.z, f.w};
    #pragma unroll
    for (int e = 0; e < 4; e++) {
      const float w = vv[e];
      const uint16_t b0 = f2bf_bits(w);
      const float r1 = w - bf_bits2f(b0);
      const uint16_t b1 = f2bf_bits(r1);
      const float r2 = r1 - bf_bits2f(b1);
      Ls[0][kr][nc + q*4 + e] = b0;
      Ls[1][kr][nc + q*4 + e] = b1;
      Ls[2][kr][nc + q*4 + e] = f2bf_bits(r2);
    }
  }
  __syncthreads();
  for (int r = tid; r < 384; r += 256) {
    const int v = r >> 7, n = r & 127;
    uint16_t tmp[32];
    #pragma unroll
    for (int k = 0; k < 32; k++) tmp[k] = Ls[v][k][n];
    uint4* dst = (uint4*)(XT + (((size_t)(inp*3 + v)*40 + tb)*384 + (n0 + n))*384 + k0);
    const uint4* s = (const uint4*)tmp;
    dst[0] = s[0]; dst[1] = s[1]; dst[2] = s[2]; dst[3] = s[3];
  }
}

// ===========================================================================
// conv1 via MFMA: 6 convs, 6-product exact-split bf16 GEMM + BN + LIF ->
// bit-packed spikes. 128x128 tile, 4 waves, BK=16.
// 3-buffer LDS, depth-2 prefetch, counted vmcnt across raw barriers (T3+T4),
// setprio around MFMA cluster (T5).
// ===========================================================================
__global__ __launch_bounds__(256) void conv1_mfma(
    const uint16_t* __restrict__ Wsplit, const uint16_t* __restrict__ XT,
    const float* __restrict__ sg, const float* __restrict__ sb,
    const float* __restrict__ tg, const float* __restrict__ tb_,
    uint32_t* __restrict__ PSq, uint32_t* __restrict__ PSk, uint32_t* __restrict__ PSv,
    uint32_t* __restrict__ PTq, uint32_t* __restrict__ PTk, uint32_t* __restrict__ PTv)
{
  const int xi = blockIdx.x;             // 0..53
  const int mt = xi / 3, ntile = xi % 3;
  const int tb_i = blockIdx.y;           // 0..39
  const int conv = mt / 3, row0 = (mt % 3) * 128, n0 = ntile * 128;
  const int t = tb_i >> 2, b = tb_i & 3;
  const int slot = (conv < 3) ? conv : conv - 3;
  const int inp = (conv == 0 || conv == 3) ? 0 : 1;

  __shared__ uint8_t lds[73728];                 // 3 x (A 12KB + B 12KB)
  __shared__ float g_l[128], b_l[128];
  const int tid = threadIdx.x, lane = tid & 63, w = tid >> 6;
  const int hi = lane >> 5, l31 = lane & 31;
  const int wr = w >> 1, wc = w & 1;

  const float* gsrc = ((conv < 3) ? sg : tg) + slot*384 + row0;
  const float* bsrc = ((conv < 3) ? sb : tb_) + slot*384 + row0;
  if (tid < 128) g_l[tid] = gsrc[tid];
  else b_l[tid - 128] = bsrc[tid - 128];
  __syncthreads();                      // g_l/b_l visible; no vmem in flight yet

  // 24 staging sets per k-step (A: s=v*4+rb in [0,12); B: 12 + v*4+cb), 6/wave
  const uint8_t* gp[6]; uint32_t loff[6];
  #pragma unroll
  for (int j = 0; j < 6; j++) {
    const int s = w*6 + j;
    if (s < 12) {
      const int v = s >> 2, rb = s & 3;
      gp[j] = (const uint8_t*)(Wsplit + ((size_t)(conv*3 + v)*384 + row0 + rb*32 + l31)*384 + 8*hi);
      loff[j] = (uint32_t)(s*1024 + lane*16);
    } else {
      const int s2 = s - 12, v = s2 >> 2, cb = s2 & 3;
      gp[j] = (const uint8_t*)(XT + (((size_t)(inp*3 + v)*40 + tb_i)*384 + n0 + cb*32 + l31)*384 + 8*hi);
      loff[j] = (uint32_t)(12288 + s2*1024 + lane*16);
    }
  }

  f32x16 acc[2][2];
  #pragma unroll
  for (int i = 0; i < 2; i++)
    #pragma unroll
    for (int j = 0; j < 2; j++)
      #pragma unroll
      for (int e = 0; e < 16; e++) acc[i][j][e] = 0.0f;

  // prologue: stage ks=0 -> buf0, ks=1 -> buf1 (12 loads in flight per wave)
  #pragma unroll
  for (int j = 0; j < 6; j++) gload_lds16(gp[j], &lds[0*24576 + loff[j]]);
  #pragma unroll
  for (int j = 0; j < 6; j++) gload_lds16(gp[j] + 32, &lds[1*24576 + loff[j]]);

  int ib = 0;                            // buffer holding k-step ks
  for (int ks = 0; ks < 24; ks++) {
    if (ks < 23) { VMCNT(6); } else { VMCNT(0); }   // wait stage(ks), keep stage(ks+1) in flight
    SBAR();
    SCHEDB();
    if (ks < 22) {                       // restage buffer read at iter ks-1
      int is = ib + 2; if (is >= 3) is -= 3;
      uint8_t* nb = &lds[is * 24576];
      #pragma unroll
      for (int j = 0; j < 6; j++)
        gload_lds16(gp[j] + (size_t)(ks + 2) * 32, &nb[loff[j]]);
    }
    const uint8_t* buf = &lds[ib * 24576];
    bf16x8 af[2][3], bfv[2][3];
    #pragma unroll
    for (int i = 0; i < 2; i++)
      #pragma unroll
      for (int v = 0; v < 3; v++) {
        af[i][v]  = *(const bf16x8*)(buf + (v*4 + wr*2 + i)*1024 + lane*16);
        bfv[i][v] = *(const bf16x8*)(buf + 12288 + (v*4 + wc*2 + i)*1024 + lane*16);
      }
    __builtin_amdgcn_s_setprio(1);
    #pragma unroll
    for (int i = 0; i < 2; i++)
      #pragma unroll
      for (int j = 0; j < 2; j++) {
        f32x16 c = acc[i][j];
        c = __builtin_amdgcn_mfma_f32_32x32x16_bf16(af[i][0], bfv[j][0], c, 0, 0, 0);
        c = __builtin_amdgcn_mfma_f32_32x32x16_bf16(af[i][0], bfv[j][1], c, 0, 0, 0);
        c = __builtin_amdgcn_mfma_f32_32x32x16_bf16(af[i][1], bfv[j][0], c, 0, 0, 0);
        c = __builtin_amdgcn_mfma_f32_32x32x16_bf16(af[i][0], bfv[j][2], c, 0, 0, 0);
        c = __builtin_amdgcn_mfma_f32_32x32x16_bf16(af[i][1], bfv[j][1], c, 0, 0, 0);
        c = __builtin_amdgcn_mfma_f32_32x32x16_bf16(af[i][2], bfv[j][0], c, 0, 0, 0);
        acc[i][j] = c;
      }
    __builtin_amdgcn_s_setprio(0);
    ib = (ib == 2) ? 0 : ib + 1;
  }

  uint32_t* Pout;
  switch (conv) {
    case 0: Pout = PSq; break;
    case 1: Pout = PSk; break;
    case 2: Pout = PSv; break;
    case 3: Pout = PTq; break;
    case 4: Pout = PTk; break;
    default: Pout = PTv; break;
  }
  #pragma unroll
  for (int i = 0; i < 2; i++) {
    const int rb = wr*2 + i;
    const int h = (row0 >> 5) + rb;
    #pragma unroll
    for (int j = 0; j < 2; j++) {
      const int cb = wc*2 + j;
      uint32_t u = 0;
      #pragma unroll
      for (int reg = 0; reg < 16; reg++) {
        const int row = (reg & 3) + 8*(reg >> 2) + 4*hi;
        const float z = acc[i][j][reg] * g_l[rb*32 + row] + b_l[rb*32 + row];
        u |= (z >= 2.0f ? 1u : 0u) << row;
      }
      u |= (uint32_t)__shfl_xor((int)u, 32, 64);
      if (hi == 0) {
        const int ncol = n0 + cb*32 + l31;
        if (conv < 3) Pout[((size_t)tb_i*12 + h)*384 + ncol] = u;
        else          Pout[(((size_t)b*12 + h)*10 + t)*384 + ncol] = u;
      }
    }
  }
}

// ===========================================================================
// conv4 via MFMA: 3-product exact bf16 GEMM (binary RHS) + BN + LIF -> bytes.
// Same counted-vmcnt 3-buffer pipeline (4 sets/wave -> vmcnt(4)).
// ===========================================================================
__global__ __launch_bounds__(256) void conv4_mfma(
    const uint16_t* __restrict__ Wsplit, const uint16_t* __restrict__ BT,
    const float* __restrict__ g, const float* __restrict__ bsh,
    uint8_t* __restrict__ Sout, int wconv)
{
  const int xi = blockIdx.x;             // 0..8
  const int mtile = xi / 3, ntile = xi % 3;
  const int tb_i = blockIdx.y;           // 0..39
  const int row0 = mtile * 128, n0 = ntile * 128;

  __shared__ uint8_t lds[49152];                 // 3 x (A 12KB + B 4KB)
  __shared__ float g_l[128], b_l[128];
  const int tid = threadIdx.x, lane = tid & 63, w = tid >> 6;
  const int hi = lane >> 5, l31 = lane & 31;
  const int wr = w >> 1, wc = w & 1;

  if (tid < 128) g_l[tid] = g[row0 + tid];
  else b_l[tid - 128] = bsh[row0 + tid - 128];
  __syncthreads();

  const uint8_t* gp[4]; uint32_t loff[4];
  #pragma unroll
  for (int j = 0; j < 4; j++) {
    const int s = w*4 + j;
    if (s < 12) {
      const int v = s >> 2, rb = s & 3;
      gp[j] = (const uint8_t*)(Wsplit + ((size_t)(wconv*3 + v)*384 + row0 + rb*32 + l31)*384 + 8*hi);
      loff[j] = (uint32_t)(s*1024 + lane*16);
    } else {
      const int cb = s - 12;
      gp[j] = (const uint8_t*)(BT + ((size_t)tb_i*384 + n0 + cb*32 + l31)*384 + 8*hi);
      loff[j] = (uint32_t)(12288 + cb*1024 + lane*16);
    }
  }

  f32x16 acc[2][2];
  #pragma unroll
  for (int i = 0; i < 2; i++)
    #pragma unroll
    for (int j = 0; j < 2; j++)
      #pragma unroll
      for (int e = 0; e < 16; e++) acc[i][j][e] = 0.0f;

  #pragma unroll
  for (int j = 0; j < 4; j++) gload_lds16(gp[j], &lds[0*16384 + loff[j]]);
  #pragma unroll
  for (int j = 0; j < 4; j++) gload_lds16(gp[j] + 32, &lds[1*16384 + loff[j]]);

  int ib = 0;
  for (int ks = 0; ks < 24; ks++) {
    if (ks < 23) { VMCNT(4); } else { VMCNT(0); }
    SBAR();
    SCHEDB();
    if (ks < 22) {
      int is = ib + 2; if (is >= 3) is -= 3;
      uint8_t* nb = &lds[is * 16384];
      #pragma unroll
      for (int j = 0; j < 4; j++)
        gload_lds16(gp[j] + (size_t)(ks + 2) * 32, &nb[loff[j]]);
    }
    const uint8_t* buf = &lds[ib * 16384];
    bf16x8 af[2][3], bfv[2];
    #pragma unroll
    for (int i = 0; i < 2; i++) {
      #pragma unroll
      for (int v = 0; v < 3; v++)
        af[i][v] = *(const bf16x8*)(buf + (v*4 + wr*2 + i)*1024 + lane*16);
      bfv[i] = *(const bf16x8*)(buf + 12288 + (wc*2 + i)*1024 + lane*16);
    }
    __builtin_amdgcn_s_setprio(1);
    #pragma unroll
    for (int i = 0; i < 2; i++)
      #pragma unroll
      for (int j = 0; j < 2; j++) {
        f32x16 c = acc[i][j];
        c = __builtin_amdgcn_mfma_f32_32x32x16_bf16(af[i][0], bfv[j], c, 0, 0, 0);
        c = __builtin_amdgcn_mfma_f32_32x32x16_bf16(af[i][1], bfv[j], c, 0, 0, 0);
        c = __builtin_amdgcn_mfma_f32_32x32x16_bf16(af[i][2], bfv[j], c, 0, 0, 0);
        acc[i][j] = c;
      }
    __builtin_amdgcn_s_setprio(0);
    ib = (ib == 2) ? 0 : ib + 1;
  }

  uint8_t* outb = Sout + (size_t)tb_i * CN_;
  #pragma unroll
  for (int i = 0; i < 2; i++) {
    const int rb = wr*2 + i;
    #pragma unroll
    for (int j = 0; j < 2; j++) {
      const int cb = wc*2 + j;
      const int n = n0 + cb*32 + l31;
      #pragma unroll
      for (int reg = 0; reg < 16; reg++) {
        const int row = (reg & 3) + 8*(reg >> 2) + 4*hi;
        const int oc = row0 + rb*32 + row;
        const float z = acc[i][j][reg] * g_l[rb*32 + row] + b_l[rb*32 + row];
        outb[(size_t)oc*384 + n] = (z >= 2.0f) ? 1 : 0;
      }
    }
  }
}

// ===========================================================================
// Spatial attention (exact ints): popcount k^T v, o = q(k^T v); spike=(o>=8).
// Output bf16 transposed BspT[tb][n][c].
// ===========================================================================
__global__ __launch_bounds__(384) void attn_spatial(
    const uint32_t* __restrict__ PSq, const uint32_t* __restrict__ PSk,
    const uint32_t* __restrict__ PSv, uint16_t* __restrict__ BspT)
{
  const int blk = blockIdx.x;                 // 0..479
  const int h = blk % 12, tb = blk / 12;
  const size_t pbase = ((size_t)tb*12 + h) * 384;

  __shared__ uint32_t qb[384], kb[384], vb[384];
  __shared__ uint32_t knT[32][12], vnT[32][12];
  __shared__ int ktv[32][33];
  const int tid = threadIdx.x;

  qb[tid] = PSq[pbase + tid];
  kb[tid] = PSk[pbase + tid];
  vb[tid] = PSv[pbase + tid];
  __syncthreads();

  {  // column-packed transposes
    const int i = tid & 31, wg = tid >> 5;
    uint32_t kk = 0, vv = 0;
    #pragma unroll
    for (int j = 0; j < 32; j++) {
      kk |= ((kb[wg*32 + j] >> i) & 1u) << j;
      vv |= ((vb[wg*32 + j] >> i) & 1u) << j;
    }
    knT[i][wg] = kk; vnT[i][wg] = vv;
  }
  __syncthreads();

  if (tid < 256) {  // ktv[i][j] = sum_n k[n,i] v[n,j]
    const int i = tid >> 3, j0 = (tid & 7) * 4;
    #pragma unroll
    for (int jj = 0; jj < 4; jj++) {
      int s = 0;
      #pragma unroll
      for (int wg = 0; wg < 12; wg++) s += __popc(knT[i][wg] & vnT[j0 + jj][wg]);
      ktv[i][j0 + jj] = s;
    }
  }
  __syncthreads();

  const int n = tid;
  uint32_t q = qb[n];
  int o[32];
  #pragma unroll
  for (int dd = 0; dd < 32; dd++) o[dd] = 0;
  while (q) {
    const int i = __ffs(q) - 1; q &= q - 1;
    #pragma unroll
    for (int dd = 0; dd < 32; dd++) o[dd] += ktv[i][dd];
  }
  uint16_t rowv[32];
  #pragma unroll
  for (int dd = 0; dd < 32; dd++) rowv[dd] = (o[dd] >= 8) ? 0x3F80 : 0;
  uint4* dst = (uint4*)(BspT + ((size_t)tb*384 + n)*384 + h*32);
  const uint4* s = (const uint4*)rowv;
  dst[0] = s[0]; dst[1] = s[1]; dst[2] = s[2]; dst[3] = s[3];
}

// Temporal attention (exact ints) -> bf16 transposed BtpT[tb2][n][c2].
// Grid (h, b, t) — one t per block for 10x the parallelism.
__global__ __launch_bounds__(384) void attn_temporal(
    const uint32_t* __restrict__ PTq, const uint32_t* __restrict__ PTk,
    const uint32_t* __restrict__ PTv, uint16_t* __restrict__ BtpT)
{
  const int n = threadIdx.x;
  const int h = blockIdx.x, b = blockIdx.y, t = blockIdx.z;
  const size_t base = ((size_t)b*12 + h) * 10 * 384 + n;

  const uint32_t q = PTq[base + (size_t)t*384];
  uint32_t kb[10], vb[10];
  #pragma unroll
  for (int s = 0; s < 10; s++) {
    kb[s] = PTk[base + (size_t)s*384];
    vb[s] = PTv[base + (size_t)s*384];
  }

  int o[32];
  #pragma unroll
  for (int dd = 0; dd < 32; dd++) o[dd] = 0;
  #pragma unroll
  for (int s = 0; s < 10; s++) {
    const int a = __popc(q & kb[s]);
    const uint32_t v = vb[s];
    #pragma unroll
    for (int dd = 0; dd < 32; dd++)
      o[dd] += (int)((v >> dd) & 1) * a;
  }
  uint16_t rowv[32];
  #pragma unroll
  for (int dd = 0; dd < 32; dd++) rowv[dd] = (o[dd] >= 8) ? 0x3F80 : 0;
  const int flat = h*320 + t*32;
  const int t2 = flat / 384, c2 = flat % 384;
  uint4* dst = (uint4*)(BtpT + ((size_t)(t2*4 + b)*384 + n)*384 + c2);
  const uint4* s4 = (const uint4*)rowv;
  dst[0] = s4[0]; dst[1] = s4[1]; dst[2] = s4[2]; dst[3] = s4[3];
}

// ===========================================================================
// reductions + final outer product
// ===========================================================================
__global__ __launch_bounds__(256) void reduce_a(const uint8_t* __restrict__ a_spike,
                                                float* __restrict__ a_red)
{
  const int row = blockIdx.x * 4 + (threadIdx.x >> 6);
  const int lane = threadIdx.x & 63;
  const uint8_t* p = a_spike + (size_t)row * 384;
  int s = 0;
  #pragma unroll
  for (int i = 0; i < 6; i++) s += p[lane + i*64];
  #pragma unroll
  for (int off = 32; off; off >>= 1) s += __shfl_down(s, off, 64);
  if (lane == 0) a_red[row] = (float)s * (1.0f / 384.0f);
}

__global__ __launch_bounds__(256) void reduce_b(const uint8_t* __restrict__ bt_spike,
                                                float* __restrict__ b_red)
{
  const int idx = blockIdx.x * 256 + threadIdx.x;
  int s = 0;
  #pragma unroll
  for (int t = 0; t < 10; t++) s += bt_spike[(size_t)t * BCN_ + idx];
  b_red[idx] = (float)s * 0.1f;
}

__global__ __launch_bounds__(256) void final_kernel(const float* __restrict__ a_red,
                                                    const float* __restrict__ b_red,
                                                    float* __restrict__ out)
{
  const int idx = blockIdx.x * 256 + threadIdx.x;
  out[idx] = a_red[idx / 384] * b_red[idx % BCN_];
}

// ===========================================================================
extern "C" void kernel_launch(void* const* d_in, const int* in_sizes, int n_in,
                              void* d_out, int out_size, void* d_ws, size_t ws_size,
                              hipStream_t stream) {
  const float* x  = (const float*)d_in[0];
  const float* y  = (const float*)d_in[1];
  const float* sW = (const float*)d_in[2];
  const float* sg = (const float*)d_in[3];
  const float* sb = (const float*)d_in[4];
  const float* tW = (const float*)d_in[5];
  const float* tg = (const float*)d_in[6];
  const float* tb = (const float*)d_in[7];
  float* out = (float*)d_out;

  uint16_t* XT   = (uint16_t*)d_ws;              // 35,389,440 elems
  uint16_t* Wsp  = XT + 35389440;                // 3,538,944 elems
  uint32_t* PSq  = (uint32_t*)(Wsp + 3538944);
  uint32_t* PSk  = PSq + PKN_;
  uint32_t* PSv  = PSk + PKN_;
  uint32_t* PTq  = PSv + PKN_;
  uint32_t* PTk  = PTq + PKN_;
  uint32_t* PTv  = PTk + PKN_;
  uint16_t* BspT = (uint16_t*)(PTv + PKN_);      // 5,898,240 elems
  uint16_t* BtpT = BspT + 5898240;
  uint8_t* a_spike  = (uint8_t*)(BtpT + 5898240);
  uint8_t* bt_spike = a_spike + TBCN_;
  float* a_red = (float*)(bt_spike + TBCN_);
  float* b_red = a_red + 15360;

  wsplit_kernel<<<4608, 256, 0, stream>>>(sW, tW, Wsp);
  xsplit_kernel<<<dim3(12, 3, 80), 256, 0, stream>>>(x, y, XT);
  conv1_mfma<<<dim3(54, 40), 256, 0, stream>>>(Wsp, XT, sg, sb, tg, tb,
                                               PSq, PSk, PSv, PTq, PTk, PTv);
  attn_spatial<<<480, 384, 0, stream>>>(PSq, PSk, PSv, BspT);
  attn_temporal<<<dim3(12, 4, 10), 384, 0, stream>>>(PTq, PTk, PTv, BtpT);
  conv4_mfma<<<dim3(9, 40), 256, 0, stream>>>(Wsp, BspT, sg + 3*384, sb + 3*384, a_spike, 6);
  conv4_mfma<<<dim3(9, 40), 256, 0, stream>>>(Wsp, BtpT, tg + 3*384, tb + 3*384, bt_spike, 7);
  reduce_a<<<3840, 256, 0, stream>>>(a_spike, a_red);
  reduce_b<<<2304, 256, 0, stream>>>(bt_spike, b_red);
  final_kernel<<<23040, 256, 0, stream>>>(a_red, b_red, out);
}

// Round 6
// 419.469 us; speedup vs baseline: 2.5613x; 1.1241x over previous
//
#include <hip/hip_runtime.h>
#include <stdint.h>

#define T_ 10
#define B_ 4
#define C_ 384
#define N_ 384
#define H_ 12
#define CN_ 147456      // C_*N_
#define TBCN_ 5898240   // T_*B_*C_*N_
#define BCN_ 589824     // B_*C_*N_
#define PKN_ 184320     // 40*12*384  (packed words per q/k/v array)

typedef short bf16x8 __attribute__((ext_vector_type(8)));
typedef float f32x16 __attribute__((ext_vector_type(16)));

#define VMCNT(N) asm volatile("s_waitcnt vmcnt(" #N ")" ::: "memory")
#define SBAR()   __builtin_amdgcn_s_barrier()
#define SCHEDB() __builtin_amdgcn_sched_barrier(0)

__device__ inline uint16_t f2bf_bits(float f) {
  uint32_t x = __float_as_uint(f);
  uint32_t r = (x + 0x7FFFu + ((x >> 16) & 1u)) >> 16;   // RNE
  return (uint16_t)r;
}
__device__ inline float bf_bits2f(uint16_t u) {
  return __uint_as_float(((uint32_t)u) << 16);
}

// async global->LDS, 16B per lane; LDS dest must be wave-uniform base + lane*16
__device__ inline void gload_lds16(const void* g, void* l) {
  __builtin_amdgcn_global_load_lds(
      (const __attribute__((address_space(1))) uint32_t*)g,
      (__attribute__((address_space(3))) uint32_t*)l, 16, 0, 0);
}

// ===========================================================================
// Weight split: 8 convs (Sq,Sk,Sv,Tq,Tk,Tv,Sproj,Tproj) -> 3 exact bf16 levels
// ===========================================================================
__global__ __launch_bounds__(256) void wsplit_kernel(
    const float* __restrict__ sW, const float* __restrict__ tW,
    uint16_t* __restrict__ Wsplit)
{
  const int idx = blockIdx.x * 256 + threadIdx.x;   // < 8*147456
  const int conv = idx / 147456, rem = idx % 147456;
  const float* src;
  switch (conv) {
    case 0: src = sW;          break;
    case 1: src = sW + CN_;    break;
    case 2: src = sW + 2*CN_;  break;
    case 3: src = tW;          break;
    case 4: src = tW + CN_;    break;
    case 5: src = tW + 2*CN_;  break;
    case 6: src = sW + 3*CN_;  break;
    default: src = tW + 3*CN_; break;
  }
  const float w = src[rem];
  const uint16_t b0 = f2bf_bits(w);
  const float r1 = w - bf_bits2f(b0);
  const uint16_t b1 = f2bf_bits(r1);
  const float r2 = r1 - bf_bits2f(b1);
  const uint16_t b2 = f2bf_bits(r2);
  Wsplit[(size_t)(conv*3 + 0)*147456 + rem] = b0;
  Wsplit[(size_t)(conv*3 + 1)*147456 + rem] = b1;
  Wsplit[(size_t)(conv*3 + 2)*147456 + rem] = b2;
}

// Split x,y into 3 exact bf16 levels, TRANSPOSED: XT[inp][v][tb][n][k].
__global__ __launch_bounds__(256) void xsplit_kernel(
    const float* __restrict__ x, const float* __restrict__ y,
    uint16_t* __restrict__ XT)
{
  const int kt = blockIdx.x;            // 0..11 -> k0
  const int nt = blockIdx.y;            // 0..2  -> n0
  const int z  = blockIdx.z;            // 0..79: inp*40+tb
  const int inp = z / 40, tb = z % 40;
  const float* in = (inp ? y : x) + (size_t)tb * CN_;
  const int k0 = kt * 32, n0 = nt * 128;
  __shared__ uint16_t Ls[3][32][132];
  const int tid = threadIdx.x;
  const int kr = tid >> 3, nc = (tid & 7) * 16;
  #pragma unroll
  for (int q = 0; q < 4; q++) {
    const float4 f = *(const float4*)(in + (size_t)(k0 + kr)*384 + n0 + nc + q*4);
    const float vv[4] = {f.x, f.y, f.z, f.w};
    #pragma unroll
    for (int e = 0; e < 4; e++) {
      const float w = vv[e];
      const uint16_t b0 = f2bf_bits(w);
      const float r1 = w - bf_bits2f(b0);
      const uint16_t b1 = f2bf_bits(r1);
      const float r2 = r1 - bf_bits2f(b1);
      Ls[0][kr][nc + q*4 + e] = b0;
      Ls[1][kr][nc + q*4 + e] = b1;
      Ls[2][kr][nc + q*4 + e] = f2bf_bits(r2);
    }
  }
  __syncthreads();
  for (int r = tid; r < 384; r += 256) {
    const int v = r >> 7, n = r & 127;
    uint16_t tmp[32];
    #pragma unroll
    for (int k = 0; k < 32; k++) tmp[k] = Ls[v][k][n];
    uint4* dst = (uint4*)(XT + (((size_t)(inp*3 + v)*40 + tb)*384 + (n0 + n))*384 + k0);
    const uint4* s = (const uint4*)tmp;
    dst[0] = s[0]; dst[1] = s[1]; dst[2] = s[2]; dst[3] = s[3];
  }
}

// ===========================================================================
// conv1 via MFMA: 6 convs, 6-product exact-split bf16 GEMM + BN + LIF ->
// bit-packed spikes. 128x128 tile, 4 waves, BK=16, 3-buffer counted-vmcnt
// pipeline (T3+T4) + setprio (T5).
// Grid: 1-D 2160 blocks, XCD-swizzled (T1): xcd = bid&7 owns 5 tb values;
// within XCD order = ntile-outer, (conv,mt)-mid, tb-inner, so the live
// B-slice (~2.9 MB) stays L2-resident and A-tiles are fetched once per XCD.
// ===========================================================================
__global__ __launch_bounds__(256) void conv1_mfma(
    const uint16_t* __restrict__ Wsplit, const uint16_t* __restrict__ XT,
    const float* __restrict__ sg, const float* __restrict__ sb,
    const float* __restrict__ tg, const float* __restrict__ tb_,
    uint32_t* __restrict__ PSq, uint32_t* __restrict__ PSk, uint32_t* __restrict__ PSv,
    uint32_t* __restrict__ PTq, uint32_t* __restrict__ PTk, uint32_t* __restrict__ PTv)
{
  // ---- XCD-aware bijective remap (2160 = 8 XCD x 270; 270 = 3 ntile x 18 cm x 5 tb) ----
  const int bid = blockIdx.x;
  const int xcd = bid & 7, pos = bid >> 3;     // pos in [0,270)
  const int ntile = pos / 90;
  const int r = pos % 90;
  const int cm = r / 5;                        // (conv,mt) in [0,18)
  const int tb_i = xcd * 5 + (r % 5);          // [0,40)
  const int conv = cm / 3, row0 = (cm % 3) * 128, n0 = ntile * 128;
  const int t = tb_i >> 2, b = tb_i & 3;
  const int slot = (conv < 3) ? conv : conv - 3;
  const int inp = (conv == 0 || conv == 3) ? 0 : 1;

  __shared__ uint8_t lds[73728];                 // 3 x (A 12KB + B 12KB)
  __shared__ float g_l[128], b_l[128];
  const int tid = threadIdx.x, lane = tid & 63, w = tid >> 6;
  const int hi = lane >> 5, l31 = lane & 31;
  const int wr = w >> 1, wc = w & 1;

  const float* gsrc = ((conv < 3) ? sg : tg) + slot*384 + row0;
  const float* bsrc = ((conv < 3) ? sb : tb_) + slot*384 + row0;
  if (tid < 128) g_l[tid] = gsrc[tid];
  else b_l[tid - 128] = bsrc[tid - 128];
  __syncthreads();                      // g_l/b_l visible; no vmem in flight yet

  // 24 staging sets per k-step (A: s=v*4+rb in [0,12); B: 12 + v*4+cb), 6/wave
  const uint8_t* gp[6]; uint32_t loff[6];
  #pragma unroll
  for (int j = 0; j < 6; j++) {
    const int s = w*6 + j;
    if (s < 12) {
      const int v = s >> 2, rb = s & 3;
      gp[j] = (const uint8_t*)(Wsplit + ((size_t)(conv*3 + v)*384 + row0 + rb*32 + l31)*384 + 8*hi);
      loff[j] = (uint32_t)(s*1024 + lane*16);
    } else {
      const int s2 = s - 12, v = s2 >> 2, cb = s2 & 3;
      gp[j] = (const uint8_t*)(XT + (((size_t)(inp*3 + v)*40 + tb_i)*384 + n0 + cb*32 + l31)*384 + 8*hi);
      loff[j] = (uint32_t)(12288 + s2*1024 + lane*16);
    }
  }

  f32x16 acc[2][2];
  #pragma unroll
  for (int i = 0; i < 2; i++)
    #pragma unroll
    for (int j = 0; j < 2; j++)
      #pragma unroll
      for (int e = 0; e < 16; e++) acc[i][j][e] = 0.0f;

  // prologue: stage ks=0 -> buf0, ks=1 -> buf1 (12 loads in flight per wave)
  #pragma unroll
  for (int j = 0; j < 6; j++) gload_lds16(gp[j], &lds[0*24576 + loff[j]]);
  #pragma unroll
  for (int j = 0; j < 6; j++) gload_lds16(gp[j] + 32, &lds[1*24576 + loff[j]]);

  int ib = 0;                            // buffer holding k-step ks
  for (int ks = 0; ks < 24; ks++) {
    if (ks < 23) { VMCNT(6); } else { VMCNT(0); }   // wait stage(ks), keep stage(ks+1) in flight
    SBAR();
    SCHEDB();
    if (ks < 22) {                       // restage buffer read at iter ks-1
      int is = ib + 2; if (is >= 3) is -= 3;
      uint8_t* nb = &lds[is * 24576];
      #pragma unroll
      for (int j = 0; j < 6; j++)
        gload_lds16(gp[j] + (size_t)(ks + 2) * 32, &nb[loff[j]]);
    }
    const uint8_t* buf = &lds[ib * 24576];
    bf16x8 af[2][3], bfv[2][3];
    #pragma unroll
    for (int i = 0; i < 2; i++)
      #pragma unroll
      for (int v = 0; v < 3; v++) {
        af[i][v]  = *(const bf16x8*)(buf + (v*4 + wr*2 + i)*1024 + lane*16);
        bfv[i][v] = *(const bf16x8*)(buf + 12288 + (v*4 + wc*2 + i)*1024 + lane*16);
      }
    __builtin_amdgcn_s_setprio(1);
    #pragma unroll
    for (int i = 0; i < 2; i++)
      #pragma unroll
      for (int j = 0; j < 2; j++) {
        f32x16 c = acc[i][j];
        c = __builtin_amdgcn_mfma_f32_32x32x16_bf16(af[i][0], bfv[j][0], c, 0, 0, 0);
        c = __builtin_amdgcn_mfma_f32_32x32x16_bf16(af[i][0], bfv[j][1], c, 0, 0, 0);
        c = __builtin_amdgcn_mfma_f32_32x32x16_bf16(af[i][1], bfv[j][0], c, 0, 0, 0);
        c = __builtin_amdgcn_mfma_f32_32x32x16_bf16(af[i][0], bfv[j][2], c, 0, 0, 0);
        c = __builtin_amdgcn_mfma_f32_32x32x16_bf16(af[i][1], bfv[j][1], c, 0, 0, 0);
        c = __builtin_amdgcn_mfma_f32_32x32x16_bf16(af[i][2], bfv[j][0], c, 0, 0, 0);
        acc[i][j] = c;
      }
    __builtin_amdgcn_s_setprio(0);
    ib = (ib == 2) ? 0 : ib + 1;
  }

  uint32_t* Pout;
  switch (conv) {
    case 0: Pout = PSq; break;
    case 1: Pout = PSk; break;
    case 2: Pout = PSv; break;
    case 3: Pout = PTq; break;
    case 4: Pout = PTk; break;
    default: Pout = PTv; break;
  }
  #pragma unroll
  for (int i = 0; i < 2; i++) {
    const int rb = wr*2 + i;
    const int h = (row0 >> 5) + rb;
    #pragma unroll
    for (int j = 0; j < 2; j++) {
      const int cb = wc*2 + j;
      uint32_t u = 0;
      #pragma unroll
      for (int reg = 0; reg < 16; reg++) {
        const int row = (reg & 3) + 8*(reg >> 2) + 4*hi;
        const float z = acc[i][j][reg] * g_l[rb*32 + row] + b_l[rb*32 + row];
        u |= (z >= 2.0f ? 1u : 0u) << row;
      }
      u |= (uint32_t)__shfl_xor((int)u, 32, 64);
      if (hi == 0) {
        const int ncol = n0 + cb*32 + l31;
        if (conv < 3) Pout[((size_t)tb_i*12 + h)*384 + ncol] = u;
        else          Pout[(((size_t)b*12 + h)*10 + t)*384 + ncol] = u;
      }
    }
  }
}

// ===========================================================================
// conv4 via MFMA: 3-product exact bf16 GEMM (binary RHS) + BN + LIF -> bytes.
// Same counted-vmcnt 3-buffer pipeline. Grid: 1-D 360, XCD-swizzled
// (360 = 8 x 45; 45 = 9 xi x 5 tb).
// ===========================================================================
__global__ __launch_bounds__(256) void conv4_mfma(
    const uint16_t* __restrict__ Wsplit, const uint16_t* __restrict__ BT,
    const float* __restrict__ g, const float* __restrict__ bsh,
    uint8_t* __restrict__ Sout, int wconv)
{
  const int bid = blockIdx.x;
  const int xcd = bid & 7, pos = bid >> 3;     // pos in [0,45)
  const int xi = pos / 5;                      // 0..8
  const int tb_i = xcd * 5 + (pos % 5);        // 0..39
  const int mtile = xi / 3, ntile = xi % 3;
  const int row0 = mtile * 128, n0 = ntile * 128;

  __shared__ uint8_t lds[49152];                 // 3 x (A 12KB + B 4KB)
  __shared__ float g_l[128], b_l[128];
  const int tid = threadIdx.x, lane = tid & 63, w = tid >> 6;
  const int hi = lane >> 5, l31 = lane & 31;
  const int wr = w >> 1, wc = w & 1;

  if (tid < 128) g_l[tid] = g[row0 + tid];
  else b_l[tid - 128] = bsh[row0 + tid - 128];
  __syncthreads();

  const uint8_t* gp[4]; uint32_t loff[4];
  #pragma unroll
  for (int j = 0; j < 4; j++) {
    const int s = w*4 + j;
    if (s < 12) {
      const int v = s >> 2, rb = s & 3;
      gp[j] = (const uint8_t*)(Wsplit + ((size_t)(wconv*3 + v)*384 + row0 + rb*32 + l31)*384 + 8*hi);
      loff[j] = (uint32_t)(s*1024 + lane*16);
    } else {
      const int cb = s - 12;
      gp[j] = (const uint8_t*)(BT + ((size_t)tb_i*384 + n0 + cb*32 + l31)*384 + 8*hi);
      loff[j] = (uint32_t)(12288 + cb*1024 + lane*16);
    }
  }

  f32x16 acc[2][2];
  #pragma unroll
  for (int i = 0; i < 2; i++)
    #pragma unroll
    for (int j = 0; j < 2; j++)
      #pragma unroll
      for (int e = 0; e < 16; e++) acc[i][j][e] = 0.0f;

  #pragma unroll
  for (int j = 0; j < 4; j++) gload_lds16(gp[j], &lds[0*16384 + loff[j]]);
  #pragma unroll
  for (int j = 0; j < 4; j++) gload_lds16(gp[j] + 32, &lds[1*16384 + loff[j]]);

  int ib = 0;
  for (int ks = 0; ks < 24; ks++) {
    if (ks < 23) { VMCNT(4); } else { VMCNT(0); }
    SBAR();
    SCHEDB();
    if (ks < 22) {
      int is = ib + 2; if (is >= 3) is -= 3;
      uint8_t* nb = &lds[is * 16384];
      #pragma unroll
      for (int j = 0; j < 4; j++)
        gload_lds16(gp[j] + (size_t)(ks + 2) * 32, &nb[loff[j]]);
    }
    const uint8_t* buf = &lds[ib * 16384];
    bf16x8 af[2][3], bfv[2];
    #pragma unroll
    for (int i = 0; i < 2; i++) {
      #pragma unroll
      for (int v = 0; v < 3; v++)
        af[i][v] = *(const bf16x8*)(buf + (v*4 + wr*2 + i)*1024 + lane*16);
      bfv[i] = *(const bf16x8*)(buf + 12288 + (wc*2 + i)*1024 + lane*16);
    }
    __builtin_amdgcn_s_setprio(1);
    #pragma unroll
    for (int i = 0; i < 2; i++)
      #pragma unroll
      for (int j = 0; j < 2; j++) {
        f32x16 c = acc[i][j];
        c = __builtin_amdgcn_mfma_f32_32x32x16_bf16(af[i][0], bfv[j], c, 0, 0, 0);
        c = __builtin_amdgcn_mfma_f32_32x32x16_bf16(af[i][1], bfv[j], c, 0, 0, 0);
        c = __builtin_amdgcn_mfma_f32_32x32x16_bf16(af[i][2], bfv[j], c, 0, 0, 0);
        acc[i][j] = c;
      }
    __builtin_amdgcn_s_setprio(0);
    ib = (ib == 2) ? 0 : ib + 1;
  }

  uint8_t* outb = Sout + (size_t)tb_i * CN_;
  #pragma unroll
  for (int i = 0; i < 2; i++) {
    const int rb = wr*2 + i;
    #pragma unroll
    for (int j = 0; j < 2; j++) {
      const int cb = wc*2 + j;
      const int n = n0 + cb*32 + l31;
      #pragma unroll
      for (int reg = 0; reg < 16; reg++) {
        const int row = (reg & 3) + 8*(reg >> 2) + 4*hi;
        const int oc = row0 + rb*32 + row;
        const float z = acc[i][j][reg] * g_l[rb*32 + row] + b_l[rb*32 + row];
        outb[(size_t)oc*384 + n] = (z >= 2.0f) ? 1 : 0;
      }
    }
  }
}

// ===========================================================================
// Spatial attention (exact ints): popcount k^T v, o = q(k^T v); spike=(o>=8).
// Output bf16 transposed BspT[tb][n][c].
// ===========================================================================
__global__ __launch_bounds__(384) void attn_spatial(
    const uint32_t* __restrict__ PSq, const uint32_t* __restrict__ PSk,
    const uint32_t* __restrict__ PSv, uint16_t* __restrict__ BspT)
{
  const int blk = blockIdx.x;                 // 0..479
  const int h = blk % 12, tb = blk / 12;
  const size_t pbase = ((size_t)tb*12 + h) * 384;

  __shared__ uint32_t qb[384], kb[384], vb[384];
  __shared__ uint32_t knT[32][12], vnT[32][12];
  __shared__ int ktv[32][33];
  const int tid = threadIdx.x;

  qb[tid] = PSq[pbase + tid];
  kb[tid] = PSk[pbase + tid];
  vb[tid] = PSv[pbase + tid];
  __syncthreads();

  {  // column-packed transposes
    const int i = tid & 31, wg = tid >> 5;
    uint32_t kk = 0, vv = 0;
    #pragma unroll
    for (int j = 0; j < 32; j++) {
      kk |= ((kb[wg*32 + j] >> i) & 1u) << j;
      vv |= ((vb[wg*32 + j] >> i) & 1u) << j;
    }
    knT[i][wg] = kk; vnT[i][wg] = vv;
  }
  __syncthreads();

  if (tid < 256) {  // ktv[i][j] = sum_n k[n,i] v[n,j]
    const int i = tid >> 3, j0 = (tid & 7) * 4;
    #pragma unroll
    for (int jj = 0; jj < 4; jj++) {
      int s = 0;
      #pragma unroll
      for (int wg = 0; wg < 12; wg++) s += __popc(knT[i][wg] & vnT[j0 + jj][wg]);
      ktv[i][j0 + jj] = s;
    }
  }
  __syncthreads();

  const int n = tid;
  uint32_t q = qb[n];
  int o[32];
  #pragma unroll
  for (int dd = 0; dd < 32; dd++) o[dd] = 0;
  while (q) {
    const int i = __ffs(q) - 1; q &= q - 1;
    #pragma unroll
    for (int dd = 0; dd < 32; dd++) o[dd] += ktv[i][dd];
  }
  uint16_t rowv[32];
  #pragma unroll
  for (int dd = 0; dd < 32; dd++) rowv[dd] = (o[dd] >= 8) ? 0x3F80 : 0;
  uint4* dst = (uint4*)(BspT + ((size_t)tb*384 + n)*384 + h*32);
  const uint4* s = (const uint4*)rowv;
  dst[0] = s[0]; dst[1] = s[1]; dst[2] = s[2]; dst[3] = s[3];
}

// Temporal attention (exact ints) -> bf16 transposed BtpT[tb2][n][c2].
__global__ __launch_bounds__(384) void attn_temporal(
    const uint32_t* __restrict__ PTq, const uint32_t* __restrict__ PTk,
    const uint32_t* __restrict__ PTv, uint16_t* __restrict__ BtpT)
{
  const int n = threadIdx.x;
  const int h = blockIdx.x, b = blockIdx.y, t = blockIdx.z;
  const size_t base = ((size_t)b*12 + h) * 10 * 384 + n;

  const uint32_t q = PTq[base + (size_t)t*384];
  uint32_t kb[10], vb[10];
  #pragma unroll
  for (int s = 0; s < 10; s++) {
    kb[s] = PTk[base + (size_t)s*384];
    vb[s] = PTv[base + (size_t)s*384];
  }

  int o[32];
  #pragma unroll
  for (int dd = 0; dd < 32; dd++) o[dd] = 0;
  #pragma unroll
  for (int s = 0; s < 10; s++) {
    const int a = __popc(q & kb[s]);
    const uint32_t v = vb[s];
    #pragma unroll
    for (int dd = 0; dd < 32; dd++)
      o[dd] += (int)((v >> dd) & 1) * a;
  }
  uint16_t rowv[32];
  #pragma unroll
  for (int dd = 0; dd < 32; dd++) rowv[dd] = (o[dd] >= 8) ? 0x3F80 : 0;
  const int flat = h*320 + t*32;
  const int t2 = flat / 384, c2 = flat % 384;
  uint4* dst = (uint4*)(BtpT + ((size_t)(t2*4 + b)*384 + n)*384 + c2);
  const uint4* s4 = (const uint4*)rowv;
  dst[0] = s4[0]; dst[1] = s4[1]; dst[2] = s4[2]; dst[3] = s4[3];
}

// ===========================================================================
// reductions + final outer product
// ===========================================================================
__global__ __launch_bounds__(256) void reduce_a(const uint8_t* __restrict__ a_spike,
                                                float* __restrict__ a_red)
{
  const int row = blockIdx.x * 4 + (threadIdx.x >> 6);
  const int lane = threadIdx.x & 63;
  const uint8_t* p = a_spike + (size_t)row * 384;
  int s = 0;
  #pragma unroll
  for (int i = 0; i < 6; i++) s += p[lane + i*64];
  #pragma unroll
  for (int off = 32; off; off >>= 1) s += __shfl_down(s, off, 64);
  if (lane == 0) a_red[row] = (float)s * (1.0f / 384.0f);
}

__global__ __launch_bounds__(256) void reduce_b(const uint8_t* __restrict__ bt_spike,
                                                float* __restrict__ b_red)
{
  const int idx = blockIdx.x * 256 + threadIdx.x;
  int s = 0;
  #pragma unroll
  for (int t = 0; t < 10; t++) s += bt_spike[(size_t)t * BCN_ + idx];
  b_red[idx] = (float)s * 0.1f;
}

__global__ __launch_bounds__(256) void final_kernel(const float* __restrict__ a_red,
                                                    const float* __restrict__ b_red,
                                                    float* __restrict__ out)
{
  const int idx = blockIdx.x * 256 + threadIdx.x;
  out[idx] = a_red[idx / 384] * b_red[idx % BCN_];
}

// ===========================================================================
extern "C" void kernel_launch(void* const* d_in, const int* in_sizes, int n_in,
                              void* d_out, int out_size, void* d_ws, size_t ws_size,
                              hipStream_t stream) {
  const float* x  = (const float*)d_in[0];
  const float* y  = (const float*)d_in[1];
  const float* sW = (const float*)d_in[2];
  const float* sg = (const float*)d_in[3];
  const float* sb = (const float*)d_in[4];
  const float* tW = (const float*)d_in[5];
  const float* tg = (const float*)d_in[6];
  const float* tb = (const float*)d_in[7];
  float* out = (float*)d_out;

  uint16_t* XT   = (uint16_t*)d_ws;              // 35,389,440 elems
  uint16_t* Wsp  = XT + 35389440;                // 3,538,944 elems
  uint32_t* PSq  = (uint32_t*)(Wsp + 3538944);
  uint32_t* PSk  = PSq + PKN_;
  uint32_t* PSv  = PSk + PKN_;
  uint32_t* PTq  = PSv + PKN_;
  uint32_t* PTk  = PTq + PKN_;
  uint32_t* PTv  = PTk + PKN_;
  uint16_t* BspT = (uint16_t*)(PTv + PKN_);      // 5,898,240 elems
  uint16_t* BtpT = BspT + 5898240;
  uint8_t* a_spike  = (uint8_t*)(BtpT + 5898240);
  uint8_t* bt_spike = a_spike + TBCN_;
  float* a_red = (float*)(bt_spike + TBCN_);
  float* b_red = a_red + 15360;

  wsplit_kernel<<<4608, 256, 0, stream>>>(sW, tW, Wsp);
  xsplit_kernel<<<dim3(12, 3, 80), 256, 0, stream>>>(x, y, XT);
  conv1_mfma<<<2160, 256, 0, stream>>>(Wsp, XT, sg, sb, tg, tb,
                                       PSq, PSk, PSv, PTq, PTk, PTv);
  attn_spatial<<<480, 384, 0, stream>>>(PSq, PSk, PSv, BspT);
  attn_temporal<<<dim3(12, 4, 10), 384, 0, stream>>>(PTq, PTk, PTv, BtpT);
  conv4_mfma<<<360, 256, 0, stream>>>(Wsp, BspT, sg + 3*384, sb + 3*384, a_spike, 6);
  conv4_mfma<<<360, 256, 0, stream>>>(Wsp, BtpT, tg + 3*384, tb + 3*384, bt_spike, 7);
  reduce_a<<<3840, 256, 0, stream>>>(a_spike, a_red);
  reduce_b<<<2304, 256, 0, stream>>>(bt_spike, b_red);
  final_kernel<<<23040, 256, 0, stream>>>(a_red, b_red, out);
}